// Round 12
// baseline (97.033 us; speedup 1.0000x reference)
//
#include <hip/hip_runtime.h>
#include <hip/hip_bf16.h>
#include <math.h>

typedef __attribute__((ext_vector_type(8))) short bf16x8;
typedef __attribute__((ext_vector_type(4))) float f32x4;

#define B_ 4
#define C_ 128
#define LOG2E 1.4426950408889634f

// ---- Path B (ws >= 27 MB) offsets: SPLIT=4 partials (proven r8/r10/r11) ----
#define PB_XT1   0ull
#define PB_XTT1  4194304ull
#define PB_OVL   8388608ull
#define PB_XT2   (PB_OVL + 0ull)
#define PB_XTT2  (PB_OVL + 1048576ull)
#define PB_XT4   (PB_OVL + 2097152ull)
#define PB_XTT4  (PB_OVL + 2359296ull)
#define PB_A2P   (PB_OVL + 2621440ull)
#define PB_ML2   (PB_OVL + 11010048ull)
#define PB_A4P   (PB_OVL + 11272192ull)
#define PB_ML4   (PB_OVL + 11796480ull)
#define PB_O1P   8388608ull
#define PB_ML1   25165824ull
#define PB_A2M   25690112ull
#define PB_A4M   26738688ull

// ---- Path A (ws >= 44302336 B, proven reachable in r9) : SPLIT=8 partials ----
#define PA_XT1   0ull
#define PA_XTT1  4194304ull
#define PA_O1P   8388608ull          // bf16 [8][4][128][4096] 32 MB
#define PA_XT2   8388608ull          // smalls live inside O1P (phase A)
#define PA_XTT2  9437184ull
#define PA_XT4   10485760ull
#define PA_XTT4  10747904ull
#define PA_A2P   11010048ull
#define PA_ML2   19398656ull
#define PA_A4P   19660800ull
#define PA_ML4   20185088ull
#define PA_ML1   41943040ull
#define PA_A2M   42991616ull
#define PA_A4M   44040192ull
#define PA_TOTAL 44302336ull

__device__ __forceinline__ float ex2(float x) { return __builtin_amdgcn_exp2f(x); }

__device__ __forceinline__ unsigned short f2bf(float f) {
    unsigned int u = __builtin_bit_cast(unsigned int, f);
    return (unsigned short)((u + 0x7FFFu + ((u >> 16) & 1u)) >> 16);
}
__device__ __forceinline__ float bf2f(unsigned short u) {
    unsigned int x = ((unsigned int)u) << 16;
    return __builtin_bit_cast(float, x);
}
__device__ __forceinline__ unsigned int pkbf(float lo, float hi) {
    union { __hip_bfloat162 h; unsigned int u; } c;
    c.h = __float22bfloat162_rn(make_float2(lo, hi));
    return c.u;
}
__device__ __forceinline__ void gload_lds16(const void* g, void* l) {
    __builtin_amdgcn_global_load_lds(
        (const __attribute__((address_space(1))) unsigned int*)g,
        (__attribute__((address_space(3))) unsigned int*)l, 16, 0, 0);
}

// ---------------- fused pool: x[B][C][64][64] -> {xt,xtT} for scales 1,2,4
__global__ __launch_bounds__(256) void pool_all(const float* __restrict__ x,
                                                unsigned short* __restrict__ xt1,
                                                unsigned short* __restrict__ xtT1,
                                                unsigned short* __restrict__ xt2,
                                                unsigned short* __restrict__ xtT2,
                                                unsigned short* __restrict__ xt4,
                                                unsigned short* __restrict__ xtT4) {
    constexpr int RS = 257;
    __shared__ float lds[32 * RS];
    const int hp4 = blockIdx.x;
    const int c0  = blockIdx.y * 32;
    const int b   = blockIdx.z;
    const int t   = threadIdx.x;

    #pragma unroll
    for (int i = 0; i < 8; ++i) {
        int e4 = (i * 256 + t) * 4;
        int ci = e4 >> 8, rem = e4 & 255;
        float4 v = *reinterpret_cast<const float4*>(
            &x[((size_t)(b * C_ + c0 + ci) * 64 + (hp4 * 4 + (rem >> 6))) * 64 + (rem & 63)]);
        *reinterpret_cast<float4*>(&lds[ci * RS + rem]) = v;
    }
    __syncthreads();

    #pragma unroll
    for (int i = 0; i < 32; ++i) {
        int v = i * 256 + t;
        int ci = v & 31, pos = v >> 5;
        xt1[((size_t)b * 4096 + hp4 * 256 + pos) * C_ + c0 + ci] = f2bf(lds[ci * RS + pos]);
    }
    #pragma unroll
    for (int i = 0; i < 32; ++i) {
        int ci = i, pos = t;
        xtT1[((size_t)(b * C_ + c0 + ci)) * 4096 + hp4 * 256 + pos] = f2bf(lds[ci * RS + pos]);
    }
    #pragma unroll
    for (int i = 0; i < 8; ++i) {
        int v = i * 256 + t;
        int ci = v & 31, pz = v >> 5;
        int r2 = pz >> 5, w2 = pz & 31;
        float s = lds[ci * RS + (2*r2)*64 + 2*w2]     + lds[ci * RS + (2*r2)*64 + 2*w2 + 1]
                + lds[ci * RS + (2*r2+1)*64 + 2*w2]   + lds[ci * RS + (2*r2+1)*64 + 2*w2 + 1];
        xt2[((size_t)b * 1024 + (hp4*2 + r2)*32 + w2) * C_ + c0 + ci] = f2bf(s * 0.25f);
    }
    #pragma unroll
    for (int i = 0; i < 8; ++i) {
        int v = i * 256 + t;
        int pz = v & 63, ci = v >> 6;
        int r2 = pz >> 5, w2 = pz & 31;
        float s = lds[ci * RS + (2*r2)*64 + 2*w2]     + lds[ci * RS + (2*r2)*64 + 2*w2 + 1]
                + lds[ci * RS + (2*r2+1)*64 + 2*w2]   + lds[ci * RS + (2*r2+1)*64 + 2*w2 + 1];
        xtT2[((size_t)(b * C_ + c0 + ci)) * 1024 + (hp4*2 + r2)*32 + w2] = f2bf(s * 0.25f);
    }
    #pragma unroll
    for (int i = 0; i < 2; ++i) {
        int v = i * 256 + t;
        int ci = v & 31, w4 = v >> 5;
        float s = 0.f;
        #pragma unroll
        for (int r = 0; r < 4; ++r)
            #pragma unroll
            for (int j = 0; j < 4; ++j) s += lds[ci * RS + r*64 + w4*4 + j];
        xt4[((size_t)b * 256 + hp4*16 + w4) * C_ + c0 + ci] = f2bf(s * 0.0625f);
    }
    #pragma unroll
    for (int i = 0; i < 2; ++i) {
        int v = i * 256 + t;
        int w4 = v & 15, ci = v >> 4;
        float s = 0.f;
        #pragma unroll
        for (int r = 0; r < 4; ++r)
            #pragma unroll
            for (int j = 0; j < 4; ++j) s += lds[ci * RS + r*64 + w4*4 + j];
        xtT4[((size_t)(b * C_ + c0 + ci)) * 256 + hp4*16 + w4] = f2bf(s * 0.0625f);
    }
}

// ---------------- MFMA flash attention, KVBLK=32, 32 KB LDS (round-11 body).
template<int N, int SPLIT>
__device__ __forceinline__ void attn_body(const unsigned short* __restrict__ xt,
                                          const unsigned short* __restrict__ xtT,
                                          unsigned short* __restrict__ op,
                                          float* __restrict__ ml,
                                          const int bid, char* lds) {
    constexpr int LOG2S = (SPLIT == 2) ? 1 : ((SPLIT == 4) ? 2 : 3);
    constexpr int QB = N / 128;
    constexpr int W2 = QB * SPLIT / 2;
    constexpr int NT = N / SPLIT / 32;
    static_assert(NT >= 2 && (NT & 1) == 0, "even NT >= 2 required");
    const int xcd   = bid & 7;
    const int b     = xcd >> 1;                 // batch pinned to XCD pair (L2 locality)
    const int wi    = (xcd & 1) * W2 + (bid >> 3);
    const int split = wi & (SPLIT - 1);
    const int qx    = wi >> LOG2S;
    const int n0    = qx * 128;
    const int m_beg = split * (N / SPLIT);

    const int tid = threadIdx.x;
    const int w = tid >> 6, lane = tid & 63;
    const int g = lane >> 4, rho = lane & 15;

    const char* xb  = (const char*)(xt  + (size_t)b * N * C_);
    const char* xtb = (const char*)(xtT + (size_t)b * C_ * N);

    bf16x8 qf[2][4];
    #pragma unroll
    for (int tt = 0; tt < 2; ++tt) {
        const char* qr = xb + (size_t)(n0 + w * 32 + tt * 16 + rho) * 256;
        #pragma unroll
        for (int kc = 0; kc < 4; ++kc) {
            bf16x8 raw = *(const bf16x8*)(qr + kc * 64 + g * 16);
            bf16x8 s;
            #pragma unroll
            for (int e = 0; e < 8; ++e)
                s[e] = (short)f2bf(bf2f((unsigned short)raw[e]) * LOG2E);
            qf[tt][kc] = s;
        }
    }

    // K tile [32 m][128 c], swizzle (row&15)<<4; V^T [128 c][32 m], swizzle ((c>>1)&3)<<4
    int kOff[2], vOff[2];
    #pragma unroll
    for (int k = 0; k < 2; ++k) {
        int D = (w * 2 + k) * 1024 + lane * 16;
        int row = D >> 8, colb = D & 255;
        kOff[k] = row * 256 + (colb ^ ((row & 15) << 4));
        int c = D >> 6, cb2 = D & 63;
        vOff[k] = c * (2 * N) + (cb2 ^ (((c >> 1) & 3) << 4));
    }
    int qkOff[2][4], pvOff[8];
    #pragma unroll
    for (int mb = 0; mb < 2; ++mb) {
        int rowm = (mb << 2) + ((rho >> 2) << 3) + (rho & 3);
        int swz = (rowm & 15) << 4;
        #pragma unroll
        for (int kc = 0; kc < 4; ++kc)
            qkOff[mb][kc] = rowm * 256 + ((kc * 64 + g * 16) ^ swz);
    }
    #pragma unroll
    for (int cb = 0; cb < 8; ++cb) {
        int c = cb * 16 + rho;
        pvOff[cb] = c * 64 + ((g * 16) ^ (((c >> 1) & 3) << 4));
    }

    char* const KB0 = lds;
    char* const KB1 = lds + 8192;
    char* const VB0 = lds + 16384;
    char* const VB1 = lds + 24576;
    const char* kG = xb  + (size_t)m_beg * 256;
    const char* vG = xtb + (size_t)m_beg * 2;

    auto stageK = [&](char* dst, int tile) {
        const char* s = kG + (size_t)tile * (32 * 256);
        #pragma unroll
        for (int k = 0; k < 2; ++k) gload_lds16(s + kOff[k], dst + (w * 2 + k) * 1024);
    };
    auto stageV = [&](char* dst, int tile) {
        const char* s = vG + (size_t)tile * (32 * 2);
        #pragma unroll
        for (int k = 0; k < 2; ++k) gload_lds16(s + vOff[k], dst + (w * 2 + k) * 1024);
    };

    f32x4 acc[2][8];
    #pragma unroll
    for (int tt = 0; tt < 2; ++tt)
        #pragma unroll
        for (int cb = 0; cb < 8; ++cb) acc[tt][cb] = (f32x4){0.f, 0.f, 0.f, 0.f};
    float m_run[2] = {-INFINITY, -INFINITY};
    float l_lane[2] = {0.f, 0.f};

    auto qkt = [&](const char* kb, f32x4 (&aS)[2][2]) {
        #pragma unroll
        for (int tt = 0; tt < 2; ++tt)
            #pragma unroll
            for (int mb = 0; mb < 2; ++mb) aS[tt][mb] = (f32x4){0.f, 0.f, 0.f, 0.f};
        #pragma unroll
        for (int mb = 0; mb < 2; ++mb)
            #pragma unroll
            for (int kc = 0; kc < 4; ++kc) {
                bf16x8 kf = *(const bf16x8*)(kb + qkOff[mb][kc]);
                aS[0][mb] = __builtin_amdgcn_mfma_f32_16x16x32_bf16(kf, qf[0][kc], aS[0][mb], 0, 0, 0);
                aS[1][mb] = __builtin_amdgcn_mfma_f32_16x16x32_bf16(kf, qf[1][kc], aS[1][mb], 0, 0, 0);
            }
    };

    auto smpv = [&](f32x4 (&aS)[2][2], const char* vb) {
        bf16x8 pb[2];
        #pragma unroll
        for (int tt = 0; tt < 2; ++tt) {
            float tm = aS[tt][0][0];
            #pragma unroll
            for (int mb = 0; mb < 2; ++mb)
                #pragma unroll
                for (int r = 0; r < 4; ++r) tm = fmaxf(tm, aS[tt][mb][r]);
            tm = fmaxf(tm, __shfl_xor(tm, 16));
            tm = fmaxf(tm, __shfl_xor(tm, 32));
            if (!__all(tm <= m_run[tt] + 6.0f)) {
                float nm = fmaxf(m_run[tt], tm);
                float sc = ex2(m_run[tt] - nm);
                l_lane[tt] *= sc;
                m_run[tt] = nm;
                #pragma unroll
                for (int cb = 0; cb < 8; ++cb) {
                    acc[tt][cb][0] *= sc; acc[tt][cb][1] *= sc;
                    acc[tt][cb][2] *= sc; acc[tt][cb][3] *= sc;
                }
            }
            float p[2][4];
            #pragma unroll
            for (int mb = 0; mb < 2; ++mb)
                #pragma unroll
                for (int r = 0; r < 4; ++r) {
                    p[mb][r] = ex2(aS[tt][mb][r] - m_run[tt]);
                    l_lane[tt] += p[mb][r];
                }
            union { bf16x8 v; unsigned int u[4]; } pk;
            pk.u[0] = pkbf(p[0][0], p[0][1]);
            pk.u[1] = pkbf(p[0][2], p[0][3]);
            pk.u[2] = pkbf(p[1][0], p[1][1]);
            pk.u[3] = pkbf(p[1][2], p[1][3]);
            pb[tt] = pk.v;
        }
        #pragma unroll
        for (int cb = 0; cb < 8; ++cb) {
            bf16x8 vf = *(const bf16x8*)(vb + pvOff[cb]);
            acc[0][cb] = __builtin_amdgcn_mfma_f32_16x16x32_bf16(vf, pb[0], acc[0][cb], 0, 0, 0);
            acc[1][cb] = __builtin_amdgcn_mfma_f32_16x16x32_bf16(vf, pb[1], acc[1][cb], 0, 0, 0);
        }
    };

    f32x4 accA[2][2], accB[2][2];

    // prologue: K0,V0,K1,V1 staged (8 loads); vmcnt ledger: 6/4/2/0
    stageK(KB0, 0); stageV(VB0, 0); stageK(KB1, 1); stageV(VB1, 1);
    asm volatile("s_waitcnt vmcnt(6)" ::: "memory");
    __builtin_amdgcn_s_barrier();
    qkt(KB0, accA);
    __builtin_amdgcn_s_barrier();
    if constexpr (NT > 2) stageK(KB0, 2);

    #pragma unroll 1
    for (int j = 0; j + 3 < NT; j += 2) {
        asm volatile("s_waitcnt vmcnt(4)" ::: "memory");
        __builtin_amdgcn_s_barrier();
        qkt(KB1, accB);
        smpv(accA, VB0);
        __builtin_amdgcn_s_barrier();
        stageK(KB1, j + 3);
        stageV(VB0, j + 2);
        asm volatile("s_waitcnt vmcnt(4)" ::: "memory");
        __builtin_amdgcn_s_barrier();
        qkt(KB0, accA);
        smpv(accB, VB1);
        __builtin_amdgcn_s_barrier();
        if (j + 4 < NT) stageK(KB0, j + 4);
        stageV(VB1, j + 3);
    }
    asm volatile("s_waitcnt vmcnt(2)" ::: "memory");
    __builtin_amdgcn_s_barrier();
    qkt(KB1, accB);
    smpv(accA, VB0);
    asm volatile("s_waitcnt vmcnt(0)" ::: "memory");
    __builtin_amdgcn_s_barrier();
    smpv(accB, VB1);

    // epilogue
    #pragma unroll
    for (int tt = 0; tt < 2; ++tt) {
        l_lane[tt] += __shfl_xor(l_lane[tt], 16);
        l_lane[tt] += __shfl_xor(l_lane[tt], 32);
        const int n = n0 + w * 32 + tt * 16 + rho;
        #pragma unroll
        for (int cb = 0; cb < 8; ++cb)
            #pragma unroll
            for (int r = 0; r < 4; ++r)
                op[((size_t)(split * B_ + b) * C_ + cb * 16 + g * 4 + r) * N + n] = f2bf(acc[tt][cb][r]);
        if (g == 0) {
            ml[((size_t)(split * B_ + b) * N + n) * 2 + 0] = m_run[tt];
            ml[((size_t)(split * B_ + b) * N + n) * 2 + 1] = l_lane[tt];
        }
    }
}

template<int SPLIT1>
__global__ __launch_bounds__(256, 2) void attn_mfma(const unsigned short* __restrict__ xt,
                                                    const unsigned short* __restrict__ xtT,
                                                    unsigned short* __restrict__ op,
                                                    float* __restrict__ ml) {
    __shared__ char lds[32768];
    attn_body<4096, SPLIT1>(xt, xtT, op, ml, (int)blockIdx.x, lds);
}

__global__ __launch_bounds__(256, 2) void attn_small(const unsigned short* __restrict__ xt2,
                                                     const unsigned short* __restrict__ xtT2,
                                                     unsigned short* __restrict__ a2p,
                                                     float* __restrict__ ml2,
                                                     const unsigned short* __restrict__ xt4,
                                                     const unsigned short* __restrict__ xtT4,
                                                     unsigned short* __restrict__ a4p,
                                                     float* __restrict__ ml4) {
    __shared__ char lds[32768];
    if (blockIdx.x < 256)
        attn_body<1024, 8>(xt2, xtT2, a2p, ml2, (int)blockIdx.x, lds);
    else
        attn_body<256, 2>(xt4, xtT4, a4p, ml4, (int)blockIdx.x - 256, lds);
}

// ---------------- merge partials: scale-2 (8-way) and scale-4 (2-way)
__global__ __launch_bounds__(256) void merge_small(const unsigned short* __restrict__ a2p,
                                                   const float* __restrict__ ml2,
                                                   const unsigned short* __restrict__ a4p,
                                                   const float* __restrict__ ml4,
                                                   unsigned short* __restrict__ a2m,
                                                   unsigned short* __restrict__ a4m) {
    int idx = blockIdx.x * 256 + threadIdx.x;
    if (idx < 4 * 128 * 1024) {
        int n = idx & 1023, c = (idx >> 10) & 127, b = idx >> 17;
        float M = -INFINITY;
        #pragma unroll
        for (int s = 0; s < 8; ++s) M = fmaxf(M, ml2[((s * 4 + b) * 1024 + n) * 2]);
        float L = 0.f, O = 0.f;
        #pragma unroll
        for (int s = 0; s < 8; ++s) {
            float wgt = ex2(ml2[((s * 4 + b) * 1024 + n) * 2] - M);
            L += ml2[((s * 4 + b) * 1024 + n) * 2 + 1] * wgt;
            O += bf2f(a2p[((size_t)((s * 4 + b) * 128 + c)) * 1024 + n]) * wgt;
        }
        a2m[((size_t)(b * 128 + c)) * 1024 + n] = f2bf(O / L);
    } else {
        int i2 = idx - 4 * 128 * 1024;
        if (i2 < 4 * 128 * 256) {
            int n = i2 & 255, c = (i2 >> 8) & 127, b = i2 >> 15;
            float M = fmaxf(ml4[((0 * 4 + b) * 256 + n) * 2], ml4[((1 * 4 + b) * 256 + n) * 2]);
            float L = 0.f, O = 0.f;
            #pragma unroll
            for (int s = 0; s < 2; ++s) {
                float wgt = ex2(ml4[((s * 4 + b) * 256 + n) * 2] - M);
                L += ml4[((s * 4 + b) * 256 + n) * 2 + 1] * wgt;
                O += bf2f(a4p[((size_t)((s * 4 + b) * 128 + c)) * 256 + n]) * wgt;
            }
            a4m[((size_t)(b * 128 + c)) * 256 + n] = f2bf(O / L);
        }
    }
}

// ---------------- bilinear upsample (half-pixel centers, clamp) from bf16 grid
template<int HS>
__device__ __forceinline__ float bilin(const unsigned short* __restrict__ a, int h, int w) {
    constexpr float sc = (float)HS / 64.0f;
    float sh = (h + 0.5f) * sc - 0.5f;
    float sw = (w + 0.5f) * sc - 0.5f;
    int h0 = (int)floorf(sh); float fh = sh - (float)h0;
    int w0 = (int)floorf(sw); float fw = sw - (float)w0;
    int h0c = max(h0, 0), h1c = min(h0 + 1, HS - 1);
    int w0c = max(w0, 0), w1c = min(w0 + 1, HS - 1);
    float v00 = bf2f(a[h0c * HS + w0c]), v01 = bf2f(a[h0c * HS + w1c]);
    float v10 = bf2f(a[h1c * HS + w0c]), v11 = bf2f(a[h1c * HS + w1c]);
    return (1.f - fh) * ((1.f - fw) * v00 + fw * v01)
         +        fh  * ((1.f - fw) * v10 + fw * v11);
}

// ---------------- scale-1 SP1-way merge + upsampled adds
template<int SP1>
__global__ __launch_bounds__(256) void combine_kernel(float* __restrict__ out,
                                                      const unsigned short* __restrict__ o1p,
                                                      const float* __restrict__ ml1,
                                                      const unsigned short* __restrict__ a2m,
                                                      const unsigned short* __restrict__ a4m) {
    int e = blockIdx.x * 256 + threadIdx.x;
    if (e >= B_ * C_ * 64 * 64) return;
    int w  = e & 63;
    int h  = (e >> 6) & 63;
    int bc = e >> 12;
    int b  = bc >> 7;
    int n  = (h << 6) | w;
    float M = -INFINITY;
    #pragma unroll
    for (int s = 0; s < SP1; ++s) M = fmaxf(M, ml1[((size_t)(s * 4 + b) * 4096 + n) * 2]);
    float num = 0.f, den = 0.f;
    #pragma unroll
    for (int s = 0; s < SP1; ++s) {
        float wgt = ex2(ml1[((size_t)(s * 4 + b) * 4096 + n) * 2] - M);
        den += ml1[((size_t)(s * 4 + b) * 4096 + n) * 2 + 1] * wgt;
        num += bf2f(o1p[((size_t)(s * 512 + bc)) * 4096 + n]) * wgt;
    }
    float v = num / den;
    v += bilin<32>(a2m + (size_t)bc * 1024, h, w);
    v += bilin<16>(a4m + (size_t)bc * 256,  h, w);
    out[e] = v;
}

extern "C" void kernel_launch(void* const* d_in, const int* in_sizes, int n_in,
                              void* d_out, int out_size, void* d_ws, size_t ws_size,
                              hipStream_t stream) {
    const float* x = (const float*)d_in[0];
    float* out = (float*)d_out;
    char* ws = (char*)d_ws;
    const bool big = ws_size >= PA_TOTAL;    // Path A: SPLIT=8 grid=1024 -> 4 blocks/CU

    unsigned short *xt1, *xtT1, *xt2, *xtT2, *xt4, *xtT4, *a2p, *a4p, *o1p, *a2m, *a4m;
    float *ml2, *ml4, *ml1;
    if (big) {
        xt1  = (unsigned short*)(ws + PA_XT1);  xtT1 = (unsigned short*)(ws + PA_XTT1);
        xt2  = (unsigned short*)(ws + PA_XT2);  xtT2 = (unsigned short*)(ws + PA_XTT2);
        xt4  = (unsigned short*)(ws + PA_XT4);  xtT4 = (unsigned short*)(ws + PA_XTT4);
        a2p  = (unsigned short*)(ws + PA_A2P);  ml2  = (float*)(ws + PA_ML2);
        a4p  = (unsigned short*)(ws + PA_A4P);  ml4  = (float*)(ws + PA_ML4);
        o1p  = (unsigned short*)(ws + PA_O1P);  ml1  = (float*)(ws + PA_ML1);
        a2m  = (unsigned short*)(ws + PA_A2M);  a4m  = (unsigned short*)(ws + PA_A4M);
    } else {
        xt1  = (unsigned short*)(ws + PB_XT1);  xtT1 = (unsigned short*)(ws + PB_XTT1);
        xt2  = (unsigned short*)(ws + PB_XT2);  xtT2 = (unsigned short*)(ws + PB_XTT2);
        xt4  = (unsigned short*)(ws + PB_XT4);  xtT4 = (unsigned short*)(ws + PB_XTT4);
        a2p  = (unsigned short*)(ws + PB_A2P);  ml2  = (float*)(ws + PB_ML2);
        a4p  = (unsigned short*)(ws + PB_A4P);  ml4  = (float*)(ws + PB_ML4);
        o1p  = (unsigned short*)(ws + PB_O1P);  ml1  = (float*)(ws + PB_ML1);
        a2m  = (unsigned short*)(ws + PB_A2M);  a4m  = (unsigned short*)(ws + PB_A4M);
    }

    // Phase A: fused pool + small scales (one launch) + their merge
    pool_all<<<dim3(16, 4, B_), 256, 0, stream>>>(x, xt1, xtT1, xt2, xtT2, xt4, xtT4);
    attn_small<<<272, 256, 0, stream>>>(xt2, xtT2, a2p, ml2, xt4, xtT4, a4p, ml4);
    merge_small<<<2560, 256, 0, stream>>>(a2p, ml2, a4p, ml4, a2m, a4m);

    // Phase B: scale-1 (o1p overwrites the overlap region) + final combine
    if (big) {
        attn_mfma<8><<<1024, 256, 0, stream>>>(xt1, xtT1, o1p, ml1);
        combine_kernel<8><<<(B_ * C_ * 64 * 64 + 255) / 256, 256, 0, stream>>>(out, o1p, ml1, a2m, a4m);
    } else {
        attn_mfma<4><<<512, 256, 0, stream>>>(xt1, xtT1, o1p, ml1);
        combine_kernel<4><<<(B_ * C_ * 64 * 64 + 255) / 256, 256, 0, stream>>>(out, o1p, ml1, a2m, a4m);
    }
}

// Round 14
// 80.859 us; speedup vs baseline: 1.2000x; 1.2000x over previous
//
#include <hip/hip_runtime.h>
#include <hip/hip_bf16.h>
#include <math.h>

typedef __attribute__((ext_vector_type(8))) short bf16x8;
typedef __attribute__((ext_vector_type(4))) float f32x4;

#define B_ 4
#define C_ 128
#define LOG2E 1.4426950408889634f

// ---- workspace layout ----
// [0, 8 MB):        xt1 + xtT1 (scale-1 staging, read-only during attn)
// [8 MB, 24 MB):    o1p  bf16 [4][4][128][4096] (scale-1 partials)
// [24 MB, 24.5 MB): ml1  f32  [4][4][4096][2]
// TAIL (disjoint from everything above — smalls live here so the FUSED attn
// launch can write o1p while small-scale blocks still read their staging):
//   deltas identical to the proven round-10 OVL layout.
#define XT1_B   0ull                      // 4 MB
#define XTT1_B  4194304ull                // 4 MB
#define O1P_B   8388608ull                // 16 MB
#define ML1_B   25165824ull               // 512 KB
#define TAIL_B  25690112ull
#define XT2_B   (TAIL_B + 0ull)           // bf16 [4][1024][128]   1 MB
#define XTT2_B  (TAIL_B + 1048576ull)     // bf16 [4][128][1024]   1 MB
#define XT4_B   (TAIL_B + 2097152ull)     // bf16 [4][256][128]    256 KB  (262144 B!)
#define XTT4_B  (TAIL_B + 2359296ull)     // bf16 [4][128][256]    256 KB
#define A2P_B   (TAIL_B + 2621440ull)     // bf16 [8][4][128][1024] 8 MB
#define ML2_B   (TAIL_B + 11010048ull)    // f32  [8][4][1024][2]  256 KB
#define A4P_B   (TAIL_B + 11272192ull)    // bf16 [2][4][128][256] 512 KB
#define ML4_B   (TAIL_B + 11796480ull)    // f32  [2][4][256][2]   16 KB
#define A2M_B   (TAIL_B + 11812864ull)    // bf16 [4][128][1024]   1 MB
#define A4M_B   (TAIL_B + 12861440ull)    // bf16 [4][128][256]    256 KB
// total = TAIL_B + 13123584 = 38,813,696 B  (<= ws; r12 proved ws >= 44302336)

__device__ __forceinline__ float ex2(float x) { return __builtin_amdgcn_exp2f(x); }

__device__ __forceinline__ unsigned short f2bf(float f) {
    unsigned int u = __builtin_bit_cast(unsigned int, f);
    return (unsigned short)((u + 0x7FFFu + ((u >> 16) & 1u)) >> 16);
}
__device__ __forceinline__ float bf2f(unsigned short u) {
    unsigned int x = ((unsigned int)u) << 16;
    return __builtin_bit_cast(float, x);
}
__device__ __forceinline__ unsigned int pkbf(float lo, float hi) {
    union { __hip_bfloat162 h; unsigned int u; } c;
    c.h = __float22bfloat162_rn(make_float2(lo, hi));
    return c.u;
}
__device__ __forceinline__ void gload_lds16(const void* g, void* l) {
    __builtin_amdgcn_global_load_lds(
        (const __attribute__((address_space(1))) unsigned int*)g,
        (__attribute__((address_space(3))) unsigned int*)l, 16, 0, 0);
}

// ---------------- fused pool: x[B][C][64][64] -> {xt,xtT} for scales 1,2,4
__global__ __launch_bounds__(256) void pool_all(const float* __restrict__ x,
                                                unsigned short* __restrict__ xt1,
                                                unsigned short* __restrict__ xtT1,
                                                unsigned short* __restrict__ xt2,
                                                unsigned short* __restrict__ xtT2,
                                                unsigned short* __restrict__ xt4,
                                                unsigned short* __restrict__ xtT4) {
    constexpr int RS = 257;
    __shared__ float lds[32 * RS];
    const int hp4 = blockIdx.x;
    const int c0  = blockIdx.y * 32;
    const int b   = blockIdx.z;
    const int t   = threadIdx.x;

    #pragma unroll
    for (int i = 0; i < 8; ++i) {
        int e4 = (i * 256 + t) * 4;
        int ci = e4 >> 8, rem = e4 & 255;
        float4 v = *reinterpret_cast<const float4*>(
            &x[((size_t)(b * C_ + c0 + ci) * 64 + (hp4 * 4 + (rem >> 6))) * 64 + (rem & 63)]);
        *reinterpret_cast<float4*>(&lds[ci * RS + rem]) = v;
    }
    __syncthreads();

    #pragma unroll
    for (int i = 0; i < 32; ++i) {
        int v = i * 256 + t;
        int ci = v & 31, pos = v >> 5;
        xt1[((size_t)b * 4096 + hp4 * 256 + pos) * C_ + c0 + ci] = f2bf(lds[ci * RS + pos]);
    }
    #pragma unroll
    for (int i = 0; i < 32; ++i) {
        int ci = i, pos = t;
        xtT1[((size_t)(b * C_ + c0 + ci)) * 4096 + hp4 * 256 + pos] = f2bf(lds[ci * RS + pos]);
    }
    #pragma unroll
    for (int i = 0; i < 8; ++i) {
        int v = i * 256 + t;
        int ci = v & 31, pz = v >> 5;
        int r2 = pz >> 5, w2 = pz & 31;
        float s = lds[ci * RS + (2*r2)*64 + 2*w2]     + lds[ci * RS + (2*r2)*64 + 2*w2 + 1]
                + lds[ci * RS + (2*r2+1)*64 + 2*w2]   + lds[ci * RS + (2*r2+1)*64 + 2*w2 + 1];
        xt2[((size_t)b * 1024 + (hp4*2 + r2)*32 + w2) * C_ + c0 + ci] = f2bf(s * 0.25f);
    }
    #pragma unroll
    for (int i = 0; i < 8; ++i) {
        int v = i * 256 + t;
        int pz = v & 63, ci = v >> 6;
        int r2 = pz >> 5, w2 = pz & 31;
        float s = lds[ci * RS + (2*r2)*64 + 2*w2]     + lds[ci * RS + (2*r2)*64 + 2*w2 + 1]
                + lds[ci * RS + (2*r2+1)*64 + 2*w2]   + lds[ci * RS + (2*r2+1)*64 + 2*w2 + 1];
        xtT2[((size_t)(b * C_ + c0 + ci)) * 1024 + (hp4*2 + r2)*32 + w2] = f2bf(s * 0.25f);
    }
    #pragma unroll
    for (int i = 0; i < 2; ++i) {
        int v = i * 256 + t;
        int ci = v & 31, w4 = v >> 5;
        float s = 0.f;
        #pragma unroll
        for (int r = 0; r < 4; ++r)
            #pragma unroll
            for (int j = 0; j < 4; ++j) s += lds[ci * RS + r*64 + w4*4 + j];
        xt4[((size_t)b * 256 + hp4*16 + w4) * C_ + c0 + ci] = f2bf(s * 0.0625f);
    }
    #pragma unroll
    for (int i = 0; i < 2; ++i) {
        int v = i * 256 + t;
        int w4 = v & 15, ci = v >> 4;
        float s = 0.f;
        #pragma unroll
        for (int r = 0; r < 4; ++r)
            #pragma unroll
            for (int j = 0; j < 4; ++j) s += lds[ci * RS + r*64 + w4*4 + j];
        xtT4[((size_t)(b * C_ + c0 + ci)) * 256 + hp4*16 + w4] = f2bf(s * 0.0625f);
    }
}

// ---------------- MFMA flash attention body (round-10, proven 88.4 µs config).
// KVBLK=64, split K/V double buffers (4 x 16 KB), counted-vmcnt schedule.
template<int N, int SPLIT>
__device__ __forceinline__ void attn_body(const unsigned short* __restrict__ xt,
                                          const unsigned short* __restrict__ xtT,
                                          unsigned short* __restrict__ op,
                                          float* __restrict__ ml,
                                          const int bid, char* lds) {
    constexpr int LOG2S = (SPLIT == 2) ? 1 : ((SPLIT == 4) ? 2 : 3);
    constexpr int QB = N / 128;
    constexpr int W2 = QB * SPLIT / 2;
    constexpr int NT = N / SPLIT / 64;
    static_assert(NT >= 2 && (NT & 1) == 0, "even NT >= 2 required");
    const int xcd   = bid & 7;
    const int b     = xcd >> 1;                 // batch pinned to XCD pair (L2 locality)
    const int wi    = (xcd & 1) * W2 + (bid >> 3);
    const int split = wi & (SPLIT - 1);
    const int qx    = wi >> LOG2S;
    const int n0    = qx * 128;
    const int m_beg = split * (N / SPLIT);

    const int tid = threadIdx.x;
    const int w = tid >> 6, lane = tid & 63;
    const int g = lane >> 4, rho = lane & 15;

    const char* xb  = (const char*)(xt  + (size_t)b * N * C_);
    const char* xtb = (const char*)(xtT + (size_t)b * C_ * N);

    bf16x8 qf[2][4];
    #pragma unroll
    for (int tt = 0; tt < 2; ++tt) {
        const char* qr = xb + (size_t)(n0 + w * 32 + tt * 16 + rho) * 256;
        #pragma unroll
        for (int kc = 0; kc < 4; ++kc) {
            bf16x8 raw = *(const bf16x8*)(qr + kc * 64 + g * 16);
            bf16x8 s;
            #pragma unroll
            for (int e = 0; e < 8; ++e)
                s[e] = (short)f2bf(bf2f((unsigned short)raw[e]) * LOG2E);
            qf[tt][kc] = s;
        }
    }

    int kOff[4], vOff[4];
    #pragma unroll
    for (int k = 0; k < 4; ++k) {
        int D = (w * 4 + k) * 1024 + lane * 16;
        int row = D >> 8, colb = D & 255;
        kOff[k] = row * 256 + (colb ^ ((row & 15) << 4));
        int c = D >> 7, cb2 = D & 127;
        vOff[k] = c * (2 * N) + (cb2 ^ ((c & 7) << 4));
    }
    int qkOff[4][4], pvOff[8][2];
    #pragma unroll
    for (int mb = 0; mb < 4; ++mb) {
        int rowm = ((mb >> 1) << 5) + ((mb & 1) << 2) + ((rho >> 2) << 3) + (rho & 3);
        int swz = (rowm & 15) << 4;
        #pragma unroll
        for (int kc = 0; kc < 4; ++kc)
            qkOff[mb][kc] = rowm * 256 + ((kc * 64 + g * 16) ^ swz);
    }
    #pragma unroll
    for (int cb = 0; cb < 8; ++cb) {
        int c = cb * 16 + rho;
        int vswz = (c & 7) << 4;
        #pragma unroll
        for (int ks = 0; ks < 2; ++ks)
            pvOff[cb][ks] = c * 128 + ((ks * 64 + g * 16) ^ vswz);
    }

    char* const KB0 = lds;
    char* const KB1 = lds + 16384;
    char* const VB0 = lds + 32768;
    char* const VB1 = lds + 49152;
    const char* kG = xb  + (size_t)m_beg * 256;
    const char* vG = xtb + (size_t)m_beg * 2;

    auto stageK = [&](char* dst, int tile) {
        const char* s = kG + (size_t)tile * (64 * 256);
        #pragma unroll
        for (int k = 0; k < 4; ++k) gload_lds16(s + kOff[k], dst + (w * 4 + k) * 1024);
    };
    auto stageV = [&](char* dst, int tile) {
        const char* s = vG + (size_t)tile * (64 * 2);
        #pragma unroll
        for (int k = 0; k < 4; ++k) gload_lds16(s + vOff[k], dst + (w * 4 + k) * 1024);
    };

    f32x4 acc[2][8];
    #pragma unroll
    for (int tt = 0; tt < 2; ++tt)
        #pragma unroll
        for (int cb = 0; cb < 8; ++cb) acc[tt][cb] = (f32x4){0.f, 0.f, 0.f, 0.f};
    float m_run[2] = {-INFINITY, -INFINITY};
    float l_lane[2] = {0.f, 0.f};

    auto qkt = [&](const char* kb, f32x4 (&aS)[2][4]) {
        #pragma unroll
        for (int tt = 0; tt < 2; ++tt)
            #pragma unroll
            for (int mb = 0; mb < 4; ++mb) aS[tt][mb] = (f32x4){0.f, 0.f, 0.f, 0.f};
        #pragma unroll
        for (int mb = 0; mb < 4; ++mb)
            #pragma unroll
            for (int kc = 0; kc < 4; ++kc) {
                bf16x8 kf = *(const bf16x8*)(kb + qkOff[mb][kc]);
                aS[0][mb] = __builtin_amdgcn_mfma_f32_16x16x32_bf16(kf, qf[0][kc], aS[0][mb], 0, 0, 0);
                aS[1][mb] = __builtin_amdgcn_mfma_f32_16x16x32_bf16(kf, qf[1][kc], aS[1][mb], 0, 0, 0);
            }
    };

    auto smpv = [&](f32x4 (&aS)[2][4], const char* vb) {
        bf16x8 pb[2][2];
        #pragma unroll
        for (int tt = 0; tt < 2; ++tt) {
            float tm = aS[tt][0][0];
            #pragma unroll
            for (int mb = 0; mb < 4; ++mb)
                #pragma unroll
                for (int r = 0; r < 4; ++r) tm = fmaxf(tm, aS[tt][mb][r]);
            tm = fmaxf(tm, __shfl_xor(tm, 16));
            tm = fmaxf(tm, __shfl_xor(tm, 32));
            if (!__all(tm <= m_run[tt] + 6.0f)) {
                float nm = fmaxf(m_run[tt], tm);
                float sc = ex2(m_run[tt] - nm);
                l_lane[tt] *= sc;
                m_run[tt] = nm;
                #pragma unroll
                for (int cb = 0; cb < 8; ++cb) {
                    acc[tt][cb][0] *= sc; acc[tt][cb][1] *= sc;
                    acc[tt][cb][2] *= sc; acc[tt][cb][3] *= sc;
                }
            }
            float p[4][4];
            #pragma unroll
            for (int mb = 0; mb < 4; ++mb)
                #pragma unroll
                for (int r = 0; r < 4; ++r) {
                    p[mb][r] = ex2(aS[tt][mb][r] - m_run[tt]);
                    l_lane[tt] += p[mb][r];
                }
            #pragma unroll
            for (int ks = 0; ks < 2; ++ks) {
                union { bf16x8 v; unsigned int u[4]; } pk;
                pk.u[0] = pkbf(p[2 * ks][0],     p[2 * ks][1]);
                pk.u[1] = pkbf(p[2 * ks][2],     p[2 * ks][3]);
                pk.u[2] = pkbf(p[2 * ks + 1][0], p[2 * ks + 1][1]);
                pk.u[3] = pkbf(p[2 * ks + 1][2], p[2 * ks + 1][3]);
                pb[tt][ks] = pk.v;
            }
        }
        #pragma unroll
        for (int cb = 0; cb < 8; ++cb)
            #pragma unroll
            for (int ks = 0; ks < 2; ++ks) {
                bf16x8 vf = *(const bf16x8*)(vb + pvOff[cb][ks]);
                acc[0][cb] = __builtin_amdgcn_mfma_f32_16x16x32_bf16(vf, pb[0][ks], acc[0][cb], 0, 0, 0);
                acc[1][cb] = __builtin_amdgcn_mfma_f32_16x16x32_bf16(vf, pb[1][ks], acc[1][cb], 0, 0, 0);
            }
    };

    f32x4 accA[2][4], accB[2][4];

    stageK(KB0, 0); stageV(VB0, 0); stageK(KB1, 1); stageV(VB1, 1);
    asm volatile("s_waitcnt vmcnt(12)" ::: "memory");
    __builtin_amdgcn_s_barrier();
    qkt(KB0, accA);
    __builtin_amdgcn_s_barrier();
    if constexpr (NT > 2) stageK(KB0, 2);

    #pragma unroll 1
    for (int j = 0; j + 3 < NT; j += 2) {
        asm volatile("s_waitcnt vmcnt(8)" ::: "memory");
        __builtin_amdgcn_s_barrier();
        qkt(KB1, accB);
        smpv(accA, VB0);
        __builtin_amdgcn_s_barrier();
        stageK(KB1, j + 3);
        stageV(VB0, j + 2);
        asm volatile("s_waitcnt vmcnt(8)" ::: "memory");
        __builtin_amdgcn_s_barrier();
        qkt(KB0, accA);
        smpv(accB, VB1);
        __builtin_amdgcn_s_barrier();
        if (j + 4 < NT) stageK(KB0, j + 4);
        stageV(VB1, j + 3);
    }
    asm volatile("s_waitcnt vmcnt(4)" ::: "memory");
    __builtin_amdgcn_s_barrier();
    qkt(KB1, accB);
    smpv(accA, VB0);
    asm volatile("s_waitcnt vmcnt(0)" ::: "memory");
    __builtin_amdgcn_s_barrier();
    smpv(accB, VB1);

    #pragma unroll
    for (int tt = 0; tt < 2; ++tt) {
        l_lane[tt] += __shfl_xor(l_lane[tt], 16);
        l_lane[tt] += __shfl_xor(l_lane[tt], 32);
        const int n = n0 + w * 32 + tt * 16 + rho;
        #pragma unroll
        for (int cb = 0; cb < 8; ++cb)
            #pragma unroll
            for (int r = 0; r < 4; ++r)
                op[((size_t)(split * B_ + b) * C_ + cb * 16 + g * 4 + r) * N + n] = f2bf(acc[tt][cb][r]);
        if (g == 0) {
            ml[((size_t)(split * B_ + b) * N + n) * 2 + 0] = m_run[tt];
            ml[((size_t)(split * B_ + b) * N + n) * 2 + 1] = l_lane[tt];
        }
    }
}

// ONE launch for all three scales. Small blocks FIRST (bid 0..271): they finish
// in a few µs and free their resident slots; scale-1 blocks (272..783) backfill.
__global__ __launch_bounds__(256, 2) void attn_fused(const unsigned short* __restrict__ xt1,
                                                     const unsigned short* __restrict__ xtT1,
                                                     unsigned short* __restrict__ o1p,
                                                     float* __restrict__ ml1,
                                                     const unsigned short* __restrict__ xt2,
                                                     const unsigned short* __restrict__ xtT2,
                                                     unsigned short* __restrict__ a2p,
                                                     float* __restrict__ ml2,
                                                     const unsigned short* __restrict__ xt4,
                                                     const unsigned short* __restrict__ xtT4,
                                                     unsigned short* __restrict__ a4p,
                                                     float* __restrict__ ml4) {
    __shared__ char lds[65536];
    const int bid = (int)blockIdx.x;
    if (bid < 256)
        attn_body<1024, 8>(xt2, xtT2, a2p, ml2, bid, lds);
    else if (bid < 272)
        attn_body<256, 2>(xt4, xtT4, a4p, ml4, bid - 256, lds);
    else
        attn_body<4096, 4>(xt1, xtT1, o1p, ml1, bid - 272, lds);
}

// ---------------- merge partials: scale-2 (8-way) and scale-4 (2-way)
__global__ __launch_bounds__(256) void merge_small(const unsigned short* __restrict__ a2p,
                                                   const float* __restrict__ ml2,
                                                   const unsigned short* __restrict__ a4p,
                                                   const float* __restrict__ ml4,
                                                   unsigned short* __restrict__ a2m,
                                                   unsigned short* __restrict__ a4m) {
    int idx = blockIdx.x * 256 + threadIdx.x;
    if (idx < 4 * 128 * 1024) {
        int n = idx & 1023, c = (idx >> 10) & 127, b = idx >> 17;
        float M = -INFINITY;
        #pragma unroll
        for (int s = 0; s < 8; ++s) M = fmaxf(M, ml2[((s * 4 + b) * 1024 + n) * 2]);
        float L = 0.f, O = 0.f;
        #pragma unroll
        for (int s = 0; s < 8; ++s) {
            float wgt = ex2(ml2[((s * 4 + b) * 1024 + n) * 2] - M);
            L += ml2[((s * 4 + b) * 1024 + n) * 2 + 1] * wgt;
            O += bf2f(a2p[((size_t)((s * 4 + b) * 128 + c)) * 1024 + n]) * wgt;
        }
        a2m[((size_t)(b * 128 + c)) * 1024 + n] = f2bf(O / L);
    } else {
        int i2 = idx - 4 * 128 * 1024;
        if (i2 < 4 * 128 * 256) {
            int n = i2 & 255, c = (i2 >> 8) & 127, b = i2 >> 15;
            float M = fmaxf(ml4[((0 * 4 + b) * 256 + n) * 2], ml4[((1 * 4 + b) * 256 + n) * 2]);
            float L = 0.f, O = 0.f;
            #pragma unroll
            for (int s = 0; s < 2; ++s) {
                float wgt = ex2(ml4[((s * 4 + b) * 256 + n) * 2] - M);
                L += ml4[((s * 4 + b) * 256 + n) * 2 + 1] * wgt;
                O += bf2f(a4p[((size_t)((s * 4 + b) * 128 + c)) * 256 + n]) * wgt;
            }
            a4m[((size_t)(b * 128 + c)) * 256 + n] = f2bf(O / L);
        }
    }
}

// ---------------- bilinear upsample (half-pixel centers, clamp) from bf16 grid
template<int HS>
__device__ __forceinline__ float bilin(const unsigned short* __restrict__ a, int h, int w) {
    constexpr float sc = (float)HS / 64.0f;
    float sh = (h + 0.5f) * sc - 0.5f;
    float sw = (w + 0.5f) * sc - 0.5f;
    int h0 = (int)floorf(sh); float fh = sh - (float)h0;
    int w0 = (int)floorf(sw); float fw = sw - (float)w0;
    int h0c = max(h0, 0), h1c = min(h0 + 1, HS - 1);
    int w0c = max(w0, 0), w1c = min(w0 + 1, HS - 1);
    float v00 = bf2f(a[h0c * HS + w0c]), v01 = bf2f(a[h0c * HS + w1c]);
    float v10 = bf2f(a[h1c * HS + w0c]), v11 = bf2f(a[h1c * HS + w1c]);
    return (1.f - fh) * ((1.f - fw) * v00 + fw * v01)
         +        fh  * ((1.f - fw) * v10 + fw * v11);
}

__global__ __launch_bounds__(256) void combine_kernel(float* __restrict__ out,
                                                      const unsigned short* __restrict__ o1p,
                                                      const float* __restrict__ ml1,
                                                      const unsigned short* __restrict__ a2m,
                                                      const unsigned short* __restrict__ a4m) {
    int e = blockIdx.x * 256 + threadIdx.x;
    if (e >= B_ * C_ * 64 * 64) return;
    int w  = e & 63;
    int h  = (e >> 6) & 63;
    int bc = e >> 12;
    int b  = bc >> 7;
    int n  = (h << 6) | w;
    float M = -INFINITY;
    #pragma unroll
    for (int s = 0; s < 4; ++s) M = fmaxf(M, ml1[((size_t)(s * 4 + b) * 4096 + n) * 2]);
    float num = 0.f, den = 0.f;
    #pragma unroll
    for (int s = 0; s < 4; ++s) {
        float wgt = ex2(ml1[((size_t)(s * 4 + b) * 4096 + n) * 2] - M);
        den += ml1[((size_t)(s * 4 + b) * 4096 + n) * 2 + 1] * wgt;
        num += bf2f(o1p[((size_t)(s * 512 + bc)) * 4096 + n]) * wgt;
    }
    float v = num / den;
    v += bilin<32>(a2m + (size_t)bc * 1024, h, w);
    v += bilin<16>(a4m + (size_t)bc * 256,  h, w);
    out[e] = v;
}

extern "C" void kernel_launch(void* const* d_in, const int* in_sizes, int n_in,
                              void* d_out, int out_size, void* d_ws, size_t ws_size,
                              hipStream_t stream) {
    const float* x = (const float*)d_in[0];
    float* out = (float*)d_out;
    char* ws = (char*)d_ws;
    unsigned short* xt1  = (unsigned short*)(ws + XT1_B);
    unsigned short* xtT1 = (unsigned short*)(ws + XTT1_B);
    unsigned short* o1p  = (unsigned short*)(ws + O1P_B);
    float*          ml1  = (float*)(ws + ML1_B);
    unsigned short* xt2  = (unsigned short*)(ws + XT2_B);
    unsigned short* xtT2 = (unsigned short*)(ws + XTT2_B);
    unsigned short* xt4  = (unsigned short*)(ws + XT4_B);
    unsigned short* xtT4 = (unsigned short*)(ws + XTT4_B);
    unsigned short* a2p  = (unsigned short*)(ws + A2P_B);
    float*          ml2  = (float*)(ws + ML2_B);
    unsigned short* a4p  = (unsigned short*)(ws + A4P_B);
    float*          ml4  = (float*)(ws + ML4_B);
    unsigned short* a2m  = (unsigned short*)(ws + A2M_B);
    unsigned short* a4m  = (unsigned short*)(ws + A4M_B);

    pool_all<<<dim3(16, 4, B_), 256, 0, stream>>>(x, xt1, xtT1, xt2, xtT2, xt4, xtT4);
    attn_fused<<<784, 256, 0, stream>>>(xt1, xtT1, o1p, ml1,
                                        xt2, xtT2, a2p, ml2,
                                        xt4, xtT4, a4p, ml4);
    merge_small<<<2560, 256, 0, stream>>>(a2p, ml2, a4p, ml4, a2m, a4m);
    combine_kernel<<<(B_ * C_ * 64 * 64 + 255) / 256, 256, 0, stream>>>(out, o1p, ml1, a2m, a4m);
}

// Round 15
// 78.127 us; speedup vs baseline: 1.2420x; 1.0350x over previous
//
#include <hip/hip_runtime.h>
#include <hip/hip_bf16.h>
#include <math.h>

typedef __attribute__((ext_vector_type(8))) short bf16x8;
typedef __attribute__((ext_vector_type(4))) float f32x4;

#define B_ 4
#define C_ 128
#define LOG2E 1.4426950408889634f

// ---- workspace layout ----
// [0, 8 MB):  xt1+xtT1 (scale-1 staging). [8,24 MB): o1p. [24,24.5): ml1.
// TAIL: small-scale staging + partials (disjoint from o1p so the fused attn
// launch can write o1p while small blocks still read their staging).
#define XT1_B   0ull                      // 4 MB
#define XTT1_B  4194304ull                // 4 MB
#define O1P_B   8388608ull                // bf16 [4][4][128][4096]  16 MB
#define ML1_B   25165824ull               // f32  [4][4][4096][2]    512 KB
#define TAIL_B  25690112ull
#define XT2_B   (TAIL_B + 0ull)           // bf16 [4][1024][128]     1 MB
#define XTT2_B  (TAIL_B + 1048576ull)     // bf16 [4][128][1024]     1 MB
#define XT4_B   (TAIL_B + 2097152ull)     // bf16 [4][256][128]      256 KB
#define XTT4_B  (TAIL_B + 2359296ull)     // bf16 [4][128][256]      256 KB
#define A2P_B   (TAIL_B + 2621440ull)     // bf16 [2][4][128][1024]  2 MB
#define ML2_B   (TAIL_B + 4718592ull)     // f32  [2][4][1024][2]    64 KB
#define A4P_B   (TAIL_B + 4784128ull)     // bf16 [2][4][128][256]   512 KB
#define ML4_B   (TAIL_B + 5308416ull)     // f32  [2][4][256][2]     16 KB
// total = TAIL_B + 5,324,800 = 31,014,912 B (ws >= 44.3 MB proven in r9/r12)

__device__ __forceinline__ float ex2(float x) { return __builtin_amdgcn_exp2f(x); }

__device__ __forceinline__ unsigned short f2bf(float f) {
    unsigned int u = __builtin_bit_cast(unsigned int, f);
    return (unsigned short)((u + 0x7FFFu + ((u >> 16) & 1u)) >> 16);
}
__device__ __forceinline__ float bf2f(unsigned short u) {
    unsigned int x = ((unsigned int)u) << 16;
    return __builtin_bit_cast(float, x);
}
__device__ __forceinline__ unsigned int pkbf(float lo, float hi) {
    union { __hip_bfloat162 h; unsigned int u; } c;
    c.h = __float22bfloat162_rn(make_float2(lo, hi));   // v_cvt_pk_bf16_f32
    return c.u;
}
__device__ __forceinline__ void gload_lds16(const void* g, void* l) {
    __builtin_amdgcn_global_load_lds(
        (const __attribute__((address_space(1))) unsigned int*)g,
        (__attribute__((address_space(3))) unsigned int*)l, 16, 0, 0);
}

// ---------------- fused pool: x[B][C][64][64] -> {xt,xtT} for scales 1,2,4
__global__ __launch_bounds__(256) void pool_all(const float* __restrict__ x,
                                                unsigned short* __restrict__ xt1,
                                                unsigned short* __restrict__ xtT1,
                                                unsigned short* __restrict__ xt2,
                                                unsigned short* __restrict__ xtT2,
                                                unsigned short* __restrict__ xt4,
                                                unsigned short* __restrict__ xtT4) {
    constexpr int RS = 257;
    __shared__ float lds[32 * RS];
    const int hp4 = blockIdx.x;
    const int c0  = blockIdx.y * 32;
    const int b   = blockIdx.z;
    const int t   = threadIdx.x;

    #pragma unroll
    for (int i = 0; i < 8; ++i) {
        int e4 = (i * 256 + t) * 4;
        int ci = e4 >> 8, rem = e4 & 255;
        float4 v = *reinterpret_cast<const float4*>(
            &x[((size_t)(b * C_ + c0 + ci) * 64 + (hp4 * 4 + (rem >> 6))) * 64 + (rem & 63)]);
        *reinterpret_cast<float4*>(&lds[ci * RS + rem]) = v;
    }
    __syncthreads();

    // scale 1, pair-packed stores (v_cvt_pk_bf16_f32 + dword store)
    #pragma unroll
    for (int i = 0; i < 16; ++i) {
        int p  = i * 256 + t;           // pair index 0..4095
        int c2 = p & 15;                // ci pair
        int pos = p >> 4;
        unsigned int v = pkbf(lds[(2 * c2) * RS + pos], lds[(2 * c2 + 1) * RS + pos]);
        *reinterpret_cast<unsigned int*>(
            &xt1[((size_t)b * 4096 + hp4 * 256 + pos) * C_ + c0 + 2 * c2]) = v;
    }
    #pragma unroll
    for (int i = 0; i < 16; ++i) {
        int p  = i * 256 + t;
        int p2 = p & 127;               // pos pair
        int ci = p >> 7;
        unsigned int v = pkbf(lds[ci * RS + 2 * p2], lds[ci * RS + 2 * p2 + 1]);
        *reinterpret_cast<unsigned int*>(
            &xtT1[((size_t)(b * C_ + c0 + ci)) * 4096 + hp4 * 256 + 2 * p2]) = v;
    }
    // scale 2
    #pragma unroll
    for (int i = 0; i < 8; ++i) {
        int v = i * 256 + t;
        int ci = v & 31, pz = v >> 5;
        int r2 = pz >> 5, w2 = pz & 31;
        float s = lds[ci * RS + (2*r2)*64 + 2*w2]     + lds[ci * RS + (2*r2)*64 + 2*w2 + 1]
                + lds[ci * RS + (2*r2+1)*64 + 2*w2]   + lds[ci * RS + (2*r2+1)*64 + 2*w2 + 1];
        xt2[((size_t)b * 1024 + (hp4*2 + r2)*32 + w2) * C_ + c0 + ci] = f2bf(s * 0.25f);
    }
    #pragma unroll
    for (int i = 0; i < 8; ++i) {
        int v = i * 256 + t;
        int pz = v & 63, ci = v >> 6;
        int r2 = pz >> 5, w2 = pz & 31;
        float s = lds[ci * RS + (2*r2)*64 + 2*w2]     + lds[ci * RS + (2*r2)*64 + 2*w2 + 1]
                + lds[ci * RS + (2*r2+1)*64 + 2*w2]   + lds[ci * RS + (2*r2+1)*64 + 2*w2 + 1];
        xtT2[((size_t)(b * C_ + c0 + ci)) * 1024 + (hp4*2 + r2)*32 + w2] = f2bf(s * 0.25f);
    }
    // scale 4
    #pragma unroll
    for (int i = 0; i < 2; ++i) {
        int v = i * 256 + t;
        int ci = v & 31, w4 = v >> 5;
        float s = 0.f;
        #pragma unroll
        for (int r = 0; r < 4; ++r)
            #pragma unroll
            for (int j = 0; j < 4; ++j) s += lds[ci * RS + r*64 + w4*4 + j];
        xt4[((size_t)b * 256 + hp4*16 + w4) * C_ + c0 + ci] = f2bf(s * 0.0625f);
    }
    #pragma unroll
    for (int i = 0; i < 2; ++i) {
        int v = i * 256 + t;
        int w4 = v & 15, ci = v >> 4;
        float s = 0.f;
        #pragma unroll
        for (int r = 0; r < 4; ++r)
            #pragma unroll
            for (int j = 0; j < 4; ++j) s += lds[ci * RS + r*64 + w4*4 + j];
        xtT4[((size_t)(b * C_ + c0 + ci)) * 256 + hp4*16 + w4] = f2bf(s * 0.0625f);
    }
}

// ---------------- MFMA flash attention body (round-10, proven config).
// KVBLK=64, split K/V double buffers (4 x 16 KB), counted-vmcnt schedule.
template<int N, int SPLIT>
__device__ __forceinline__ void attn_body(const unsigned short* __restrict__ xt,
                                          const unsigned short* __restrict__ xtT,
                                          unsigned short* __restrict__ op,
                                          float* __restrict__ ml,
                                          const int bid, char* lds) {
    constexpr int LOG2S = (SPLIT == 2) ? 1 : ((SPLIT == 4) ? 2 : 3);
    constexpr int QB = N / 128;
    constexpr int W2 = QB * SPLIT / 2;
    constexpr int NT = N / SPLIT / 64;
    static_assert(NT >= 2 && (NT & 1) == 0, "even NT >= 2 required");
    const int xcd   = bid & 7;
    const int b     = xcd >> 1;                 // batch pinned to XCD pair (L2 locality)
    const int wi    = (xcd & 1) * W2 + (bid >> 3);
    const int split = wi & (SPLIT - 1);
    const int qx    = wi >> LOG2S;
    const int n0    = qx * 128;
    const int m_beg = split * (N / SPLIT);

    const int tid = threadIdx.x;
    const int w = tid >> 6, lane = tid & 63;
    const int g = lane >> 4, rho = lane & 15;

    const char* xb  = (const char*)(xt  + (size_t)b * N * C_);
    const char* xtb = (const char*)(xtT + (size_t)b * C_ * N);

    bf16x8 qf[2][4];
    #pragma unroll
    for (int tt = 0; tt < 2; ++tt) {
        const char* qr = xb + (size_t)(n0 + w * 32 + tt * 16 + rho) * 256;
        #pragma unroll
        for (int kc = 0; kc < 4; ++kc) {
            bf16x8 raw = *(const bf16x8*)(qr + kc * 64 + g * 16);
            bf16x8 s;
            #pragma unroll
            for (int e = 0; e < 8; ++e)
                s[e] = (short)f2bf(bf2f((unsigned short)raw[e]) * LOG2E);
            qf[tt][kc] = s;
        }
    }

    int kOff[4], vOff[4];
    #pragma unroll
    for (int k = 0; k < 4; ++k) {
        int D = (w * 4 + k) * 1024 + lane * 16;
        int row = D >> 8, colb = D & 255;
        kOff[k] = row * 256 + (colb ^ ((row & 15) << 4));
        int c = D >> 7, cb2 = D & 127;
        vOff[k] = c * (2 * N) + (cb2 ^ ((c & 7) << 4));
    }
    int qkOff[4][4], pvOff[8][2];
    #pragma unroll
    for (int mb = 0; mb < 4; ++mb) {
        int rowm = ((mb >> 1) << 5) + ((mb & 1) << 2) + ((rho >> 2) << 3) + (rho & 3);
        int swz = (rowm & 15) << 4;
        #pragma unroll
        for (int kc = 0; kc < 4; ++kc)
            qkOff[mb][kc] = rowm * 256 + ((kc * 64 + g * 16) ^ swz);
    }
    #pragma unroll
    for (int cb = 0; cb < 8; ++cb) {
        int c = cb * 16 + rho;
        int vswz = (c & 7) << 4;
        #pragma unroll
        for (int ks = 0; ks < 2; ++ks)
            pvOff[cb][ks] = c * 128 + ((ks * 64 + g * 16) ^ vswz);
    }

    char* const KB0 = lds;
    char* const KB1 = lds + 16384;
    char* const VB0 = lds + 32768;
    char* const VB1 = lds + 49152;
    const char* kG = xb  + (size_t)m_beg * 256;
    const char* vG = xtb + (size_t)m_beg * 2;

    auto stageK = [&](char* dst, int tile) {
        const char* s = kG + (size_t)tile * (64 * 256);
        #pragma unroll
        for (int k = 0; k < 4; ++k) gload_lds16(s + kOff[k], dst + (w * 4 + k) * 1024);
    };
    auto stageV = [&](char* dst, int tile) {
        const char* s = vG + (size_t)tile * (64 * 2);
        #pragma unroll
        for (int k = 0; k < 4; ++k) gload_lds16(s + vOff[k], dst + (w * 4 + k) * 1024);
    };

    f32x4 acc[2][8];
    #pragma unroll
    for (int tt = 0; tt < 2; ++tt)
        #pragma unroll
        for (int cb = 0; cb < 8; ++cb) acc[tt][cb] = (f32x4){0.f, 0.f, 0.f, 0.f};
    float m_run[2] = {-INFINITY, -INFINITY};
    float l_lane[2] = {0.f, 0.f};

    auto qkt = [&](const char* kb, f32x4 (&aS)[2][4]) {
        #pragma unroll
        for (int tt = 0; tt < 2; ++tt)
            #pragma unroll
            for (int mb = 0; mb < 4; ++mb) aS[tt][mb] = (f32x4){0.f, 0.f, 0.f, 0.f};
        #pragma unroll
        for (int mb = 0; mb < 4; ++mb)
            #pragma unroll
            for (int kc = 0; kc < 4; ++kc) {
                bf16x8 kf = *(const bf16x8*)(kb + qkOff[mb][kc]);
                aS[0][mb] = __builtin_amdgcn_mfma_f32_16x16x32_bf16(kf, qf[0][kc], aS[0][mb], 0, 0, 0);
                aS[1][mb] = __builtin_amdgcn_mfma_f32_16x16x32_bf16(kf, qf[1][kc], aS[1][mb], 0, 0, 0);
            }
    };

    auto smpv = [&](f32x4 (&aS)[2][4], const char* vb) {
        bf16x8 pb[2][2];
        #pragma unroll
        for (int tt = 0; tt < 2; ++tt) {
            float tm = aS[tt][0][0];
            #pragma unroll
            for (int mb = 0; mb < 4; ++mb)
                #pragma unroll
                for (int r = 0; r < 4; ++r) tm = fmaxf(tm, aS[tt][mb][r]);
            tm = fmaxf(tm, __shfl_xor(tm, 16));
            tm = fmaxf(tm, __shfl_xor(tm, 32));
            if (!__all(tm <= m_run[tt] + 6.0f)) {
                float nm = fmaxf(m_run[tt], tm);
                float sc = ex2(m_run[tt] - nm);
                l_lane[tt] *= sc;
                m_run[tt] = nm;
                #pragma unroll
                for (int cb = 0; cb < 8; ++cb) {
                    acc[tt][cb][0] *= sc; acc[tt][cb][1] *= sc;
                    acc[tt][cb][2] *= sc; acc[tt][cb][3] *= sc;
                }
            }
            float p[4][4];
            #pragma unroll
            for (int mb = 0; mb < 4; ++mb)
                #pragma unroll
                for (int r = 0; r < 4; ++r) {
                    p[mb][r] = ex2(aS[tt][mb][r] - m_run[tt]);
                    l_lane[tt] += p[mb][r];
                }
            #pragma unroll
            for (int ks = 0; ks < 2; ++ks) {
                union { bf16x8 v; unsigned int u[4]; } pk;
                pk.u[0] = pkbf(p[2 * ks][0],     p[2 * ks][1]);
                pk.u[1] = pkbf(p[2 * ks][2],     p[2 * ks][3]);
                pk.u[2] = pkbf(p[2 * ks + 1][0], p[2 * ks + 1][1]);
                pk.u[3] = pkbf(p[2 * ks + 1][2], p[2 * ks + 1][3]);
                pb[tt][ks] = pk.v;
            }
        }
        #pragma unroll
        for (int cb = 0; cb < 8; ++cb)
            #pragma unroll
            for (int ks = 0; ks < 2; ++ks) {
                bf16x8 vf = *(const bf16x8*)(vb + pvOff[cb][ks]);
                acc[0][cb] = __builtin_amdgcn_mfma_f32_16x16x32_bf16(vf, pb[0][ks], acc[0][cb], 0, 0, 0);
                acc[1][cb] = __builtin_amdgcn_mfma_f32_16x16x32_bf16(vf, pb[1][ks], acc[1][cb], 0, 0, 0);
            }
    };

    f32x4 accA[2][4], accB[2][4];

    stageK(KB0, 0); stageV(VB0, 0); stageK(KB1, 1); stageV(VB1, 1);
    asm volatile("s_waitcnt vmcnt(12)" ::: "memory");
    __builtin_amdgcn_s_barrier();
    qkt(KB0, accA);
    __builtin_amdgcn_s_barrier();
    if constexpr (NT > 2) stageK(KB0, 2);

    #pragma unroll 1
    for (int j = 0; j + 3 < NT; j += 2) {
        asm volatile("s_waitcnt vmcnt(8)" ::: "memory");
        __builtin_amdgcn_s_barrier();
        qkt(KB1, accB);
        smpv(accA, VB0);
        __builtin_amdgcn_s_barrier();
        stageK(KB1, j + 3);
        stageV(VB0, j + 2);
        asm volatile("s_waitcnt vmcnt(8)" ::: "memory");
        __builtin_amdgcn_s_barrier();
        qkt(KB0, accA);
        smpv(accB, VB1);
        __builtin_amdgcn_s_barrier();
        if (j + 4 < NT) stageK(KB0, j + 4);
        stageV(VB1, j + 3);
    }
    asm volatile("s_waitcnt vmcnt(4)" ::: "memory");
    __builtin_amdgcn_s_barrier();
    qkt(KB1, accB);
    smpv(accA, VB0);
    asm volatile("s_waitcnt vmcnt(0)" ::: "memory");
    __builtin_amdgcn_s_barrier();
    smpv(accB, VB1);

    #pragma unroll
    for (int tt = 0; tt < 2; ++tt) {
        l_lane[tt] += __shfl_xor(l_lane[tt], 16);
        l_lane[tt] += __shfl_xor(l_lane[tt], 32);
        const int n = n0 + w * 32 + tt * 16 + rho;
        #pragma unroll
        for (int cb = 0; cb < 8; ++cb)
            #pragma unroll
            for (int r = 0; r < 4; ++r)
                op[((size_t)(split * B_ + b) * C_ + cb * 16 + g * 4 + r) * N + n] = f2bf(acc[tt][cb][r]);
        if (g == 0) {
            ml[((size_t)(split * B_ + b) * N + n) * 2 + 0] = m_run[tt];
            ml[((size_t)(split * B_ + b) * N + n) * 2 + 1] = l_lane[tt];
        }
    }
}

// ONE launch for all three scales. Small blocks FIRST (80 of them: 64 scale-2
// SPLIT=2 + 16 scale-4 SPLIT=2); scale-1 blocks (80..591) backfill their slots.
__global__ __launch_bounds__(256, 2) void attn_fused(const unsigned short* __restrict__ xt1,
                                                     const unsigned short* __restrict__ xtT1,
                                                     unsigned short* __restrict__ o1p,
                                                     float* __restrict__ ml1,
                                                     const unsigned short* __restrict__ xt2,
                                                     const unsigned short* __restrict__ xtT2,
                                                     unsigned short* __restrict__ a2p,
                                                     float* __restrict__ ml2,
                                                     const unsigned short* __restrict__ xt4,
                                                     const unsigned short* __restrict__ xtT4,
                                                     unsigned short* __restrict__ a4p,
                                                     float* __restrict__ ml4) {
    __shared__ char lds[65536];
    const int bid = (int)blockIdx.x;
    if (bid < 64)
        attn_body<1024, 2>(xt2, xtT2, a2p, ml2, bid, lds);
    else if (bid < 80)
        attn_body<256, 2>(xt4, xtT4, a4p, ml4, bid - 64, lds);
    else
        attn_body<4096, 4>(xt1, xtT1, o1p, ml1, bid - 80, lds);
}

// ---------------- fused merge + upsample + scale-1 merge.
// One block per (b,c): 2-way-merge scale-2/4 partials into LDS (f32), then
// per-pixel scale-1 4-way merge + two bilinear adds from LDS.
__global__ __launch_bounds__(256) void combine2(float* __restrict__ out,
                                                const unsigned short* __restrict__ o1p,
                                                const float* __restrict__ ml1,
                                                const unsigned short* __restrict__ a2p,
                                                const float* __restrict__ ml2,
                                                const unsigned short* __restrict__ a4p,
                                                const float* __restrict__ ml4) {
    __shared__ float a2s[1024];
    __shared__ float a4s[256];
    const int bc = (int)blockIdx.x;
    const int b  = bc >> 7;
    const int c  = bc & 127;
    const int t  = threadIdx.x;

    #pragma unroll
    for (int i = 0; i < 4; ++i) {
        int n = i * 256 + t;
        float m0 = ml2[((0 * 4 + b) * 1024 + n) * 2], l0 = ml2[((0 * 4 + b) * 1024 + n) * 2 + 1];
        float m1 = ml2[((1 * 4 + b) * 1024 + n) * 2], l1 = ml2[((1 * 4 + b) * 1024 + n) * 2 + 1];
        float M  = fmaxf(m0, m1);
        float w0 = ex2(m0 - M), w1 = ex2(m1 - M);
        float O  = bf2f(a2p[((size_t)((0 * 4 + b) * 128 + c)) * 1024 + n]) * w0
                 + bf2f(a2p[((size_t)((1 * 4 + b) * 128 + c)) * 1024 + n]) * w1;
        a2s[n] = O / (l0 * w0 + l1 * w1);
    }
    {
        int n = t;
        float m0 = ml4[((0 * 4 + b) * 256 + n) * 2], l0 = ml4[((0 * 4 + b) * 256 + n) * 2 + 1];
        float m1 = ml4[((1 * 4 + b) * 256 + n) * 2], l1 = ml4[((1 * 4 + b) * 256 + n) * 2 + 1];
        float M  = fmaxf(m0, m1);
        float w0 = ex2(m0 - M), w1 = ex2(m1 - M);
        float O  = bf2f(a4p[((size_t)((0 * 4 + b) * 128 + c)) * 256 + n]) * w0
                 + bf2f(a4p[((size_t)((1 * 4 + b) * 128 + c)) * 256 + n]) * w1;
        a4s[n] = O / (l0 * w0 + l1 * w1);
    }
    __syncthreads();

    #pragma unroll
    for (int i = 0; i < 16; ++i) {
        int e = i * 256 + t;                 // pixel within (b,c): n = e
        int h = e >> 6, w = e & 63;
        // scale-1 4-way merge
        float M = -INFINITY;
        #pragma unroll
        for (int s = 0; s < 4; ++s) M = fmaxf(M, ml1[((size_t)(s * 4 + b) * 4096 + e) * 2]);
        float num = 0.f, den = 0.f;
        #pragma unroll
        for (int s = 0; s < 4; ++s) {
            float wgt = ex2(ml1[((size_t)(s * 4 + b) * 4096 + e) * 2] - M);
            den += ml1[((size_t)(s * 4 + b) * 4096 + e) * 2 + 1] * wgt;
            num += bf2f(o1p[((size_t)(s * 512 + bc)) * 4096 + e]) * wgt;
        }
        float v = num / den;
        // bilinear scale-2 (32x32, half-pixel, clamp)
        {
            float sh = (h + 0.5f) * 0.5f - 0.5f;
            float sw = (w + 0.5f) * 0.5f - 0.5f;
            int h0 = (int)floorf(sh); float fh = sh - (float)h0;
            int w0 = (int)floorf(sw); float fw = sw - (float)w0;
            int h0c = max(h0, 0), h1c = min(h0 + 1, 31);
            int w0c = max(w0, 0), w1c = min(w0 + 1, 31);
            float v00 = a2s[h0c * 32 + w0c], v01 = a2s[h0c * 32 + w1c];
            float v10 = a2s[h1c * 32 + w0c], v11 = a2s[h1c * 32 + w1c];
            v += (1.f - fh) * ((1.f - fw) * v00 + fw * v01)
               +        fh  * ((1.f - fw) * v10 + fw * v11);
        }
        // bilinear scale-4 (16x16)
        {
            float sh = (h + 0.5f) * 0.25f - 0.5f;
            float sw = (w + 0.5f) * 0.25f - 0.5f;
            int h0 = (int)floorf(sh); float fh = sh - (float)h0;
            int w0 = (int)floorf(sw); float fw = sw - (float)w0;
            int h0c = max(h0, 0), h1c = min(h0 + 1, 15);
            int w0c = max(w0, 0), w1c = min(w0 + 1, 15);
            float v00 = a4s[h0c * 16 + w0c], v01 = a4s[h0c * 16 + w1c];
            float v10 = a4s[h1c * 16 + w0c], v11 = a4s[h1c * 16 + w1c];
            v += (1.f - fh) * ((1.f - fw) * v00 + fw * v01)
               +        fh  * ((1.f - fw) * v10 + fw * v11);
        }
        out[(size_t)bc * 4096 + e] = v;
    }
}

extern "C" void kernel_launch(void* const* d_in, const int* in_sizes, int n_in,
                              void* d_out, int out_size, void* d_ws, size_t ws_size,
                              hipStream_t stream) {
    const float* x = (const float*)d_in[0];
    float* out = (float*)d_out;
    char* ws = (char*)d_ws;
    unsigned short* xt1  = (unsigned short*)(ws + XT1_B);
    unsigned short* xtT1 = (unsigned short*)(ws + XTT1_B);
    unsigned short* o1p  = (unsigned short*)(ws + O1P_B);
    float*          ml1  = (float*)(ws + ML1_B);
    unsigned short* xt2  = (unsigned short*)(ws + XT2_B);
    unsigned short* xtT2 = (unsigned short*)(ws + XTT2_B);
    unsigned short* xt4  = (unsigned short*)(ws + XT4_B);
    unsigned short* xtT4 = (unsigned short*)(ws + XTT4_B);
    unsigned short* a2p  = (unsigned short*)(ws + A2P_B);
    float*          ml2  = (float*)(ws + ML2_B);
    unsigned short* a4p  = (unsigned short*)(ws + A4P_B);
    float*          ml4  = (float*)(ws + ML4_B);

    pool_all<<<dim3(16, 4, B_), 256, 0, stream>>>(x, xt1, xtT1, xt2, xtT2, xt4, xtT4);
    attn_fused<<<592, 256, 0, stream>>>(xt1, xtT1, o1p, ml1,
                                        xt2, xtT2, a2p, ml2,
                                        xt4, xtT4, a4p, ml4);
    combine2<<<512, 256, 0, stream>>>(out, o1p, ml1, a2p, ml2, a4p, ml4);
}

// Round 16
// 75.656 us; speedup vs baseline: 1.2826x; 1.0327x over previous
//
#include <hip/hip_runtime.h>
#include <hip/hip_bf16.h>
#include <math.h>

typedef __attribute__((ext_vector_type(8))) short bf16x8;
typedef __attribute__((ext_vector_type(4))) float f32x4;

#define B_ 4
#define C_ 128
#define LOG2E 1.4426950408889634f

// ---- workspace layout ----
// [0, 8 MB):  xt1+xtT1 (scale-1 staging). [8,24 MB): o1p. [24,24.5): ml1.
// TAIL: small-scale staging + partials (disjoint from o1p so the fused attn
// launch can write o1p while small blocks still read their staging).
#define XT1_B   0ull                      // 4 MB
#define XTT1_B  4194304ull                // 4 MB
#define O1P_B   8388608ull                // bf16 [4][4][128][4096]  16 MB
#define ML1_B   25165824ull               // f32  [4][4][4096][2]    512 KB
#define TAIL_B  25690112ull
#define XT2_B   (TAIL_B + 0ull)           // bf16 [4][1024][128]     1 MB
#define XTT2_B  (TAIL_B + 1048576ull)     // bf16 [4][128][1024]     1 MB
#define XT4_B   (TAIL_B + 2097152ull)     // bf16 [4][256][128]      256 KB
#define XTT4_B  (TAIL_B + 2359296ull)     // bf16 [4][128][256]      256 KB
#define A2P_B   (TAIL_B + 2621440ull)     // bf16 [8][4][128][1024]  8 MB
#define ML2_B   (TAIL_B + 11010048ull)    // f32  [8][4][1024][2]    256 KB
#define A4P_B   (TAIL_B + 11272192ull)    // bf16 [2][4][128][256]   512 KB
#define ML4_B   (TAIL_B + 11796480ull)    // f32  [2][4][256][2]     16 KB
// total = TAIL_B + 11,812,864 = 37,502,976 B (ws >= 44.3 MB proven in r9/r12)

__device__ __forceinline__ float ex2(float x) { return __builtin_amdgcn_exp2f(x); }

__device__ __forceinline__ unsigned short f2bf(float f) {
    unsigned int u = __builtin_bit_cast(unsigned int, f);
    return (unsigned short)((u + 0x7FFFu + ((u >> 16) & 1u)) >> 16);
}
__device__ __forceinline__ float bf2f(unsigned short u) {
    unsigned int x = ((unsigned int)u) << 16;
    return __builtin_bit_cast(float, x);
}
__device__ __forceinline__ unsigned int pkbf(float lo, float hi) {
    union { __hip_bfloat162 h; unsigned int u; } c;
    c.h = __float22bfloat162_rn(make_float2(lo, hi));   // v_cvt_pk_bf16_f32
    return c.u;
}
__device__ __forceinline__ void gload_lds16(const void* g, void* l) {
    __builtin_amdgcn_global_load_lds(
        (const __attribute__((address_space(1))) unsigned int*)g,
        (__attribute__((address_space(3))) unsigned int*)l, 16, 0, 0);
}

// ---------------- fused pool: x[B][C][64][64] -> {xt,xtT} for scales 1,2,4
__global__ __launch_bounds__(256) void pool_all(const float* __restrict__ x,
                                                unsigned short* __restrict__ xt1,
                                                unsigned short* __restrict__ xtT1,
                                                unsigned short* __restrict__ xt2,
                                                unsigned short* __restrict__ xtT2,
                                                unsigned short* __restrict__ xt4,
                                                unsigned short* __restrict__ xtT4) {
    constexpr int RS = 257;
    __shared__ float lds[32 * RS];
    const int hp4 = blockIdx.x;
    const int c0  = blockIdx.y * 32;
    const int b   = blockIdx.z;
    const int t   = threadIdx.x;

    #pragma unroll
    for (int i = 0; i < 8; ++i) {
        int e4 = (i * 256 + t) * 4;
        int ci = e4 >> 8, rem = e4 & 255;
        float4 v = *reinterpret_cast<const float4*>(
            &x[((size_t)(b * C_ + c0 + ci) * 64 + (hp4 * 4 + (rem >> 6))) * 64 + (rem & 63)]);
        *reinterpret_cast<float4*>(&lds[ci * RS + rem]) = v;
    }
    __syncthreads();

    // scale 1, pair-packed stores (v_cvt_pk_bf16_f32 + dword store)
    #pragma unroll
    for (int i = 0; i < 16; ++i) {
        int p  = i * 256 + t;
        int c2 = p & 15;
        int pos = p >> 4;
        unsigned int v = pkbf(lds[(2 * c2) * RS + pos], lds[(2 * c2 + 1) * RS + pos]);
        *reinterpret_cast<unsigned int*>(
            &xt1[((size_t)b * 4096 + hp4 * 256 + pos) * C_ + c0 + 2 * c2]) = v;
    }
    #pragma unroll
    for (int i = 0; i < 16; ++i) {
        int p  = i * 256 + t;
        int p2 = p & 127;
        int ci = p >> 7;
        unsigned int v = pkbf(lds[ci * RS + 2 * p2], lds[ci * RS + 2 * p2 + 1]);
        *reinterpret_cast<unsigned int*>(
            &xtT1[((size_t)(b * C_ + c0 + ci)) * 4096 + hp4 * 256 + 2 * p2]) = v;
    }
    // scale 2
    #pragma unroll
    for (int i = 0; i < 8; ++i) {
        int v = i * 256 + t;
        int ci = v & 31, pz = v >> 5;
        int r2 = pz >> 5, w2 = pz & 31;
        float s = lds[ci * RS + (2*r2)*64 + 2*w2]     + lds[ci * RS + (2*r2)*64 + 2*w2 + 1]
                + lds[ci * RS + (2*r2+1)*64 + 2*w2]   + lds[ci * RS + (2*r2+1)*64 + 2*w2 + 1];
        xt2[((size_t)b * 1024 + (hp4*2 + r2)*32 + w2) * C_ + c0 + ci] = f2bf(s * 0.25f);
    }
    #pragma unroll
    for (int i = 0; i < 8; ++i) {
        int v = i * 256 + t;
        int pz = v & 63, ci = v >> 6;
        int r2 = pz >> 5, w2 = pz & 31;
        float s = lds[ci * RS + (2*r2)*64 + 2*w2]     + lds[ci * RS + (2*r2)*64 + 2*w2 + 1]
                + lds[ci * RS + (2*r2+1)*64 + 2*w2]   + lds[ci * RS + (2*r2+1)*64 + 2*w2 + 1];
        xtT2[((size_t)(b * C_ + c0 + ci)) * 1024 + (hp4*2 + r2)*32 + w2] = f2bf(s * 0.25f);
    }
    // scale 4
    #pragma unroll
    for (int i = 0; i < 2; ++i) {
        int v = i * 256 + t;
        int ci = v & 31, w4 = v >> 5;
        float s = 0.f;
        #pragma unroll
        for (int r = 0; r < 4; ++r)
            #pragma unroll
            for (int j = 0; j < 4; ++j) s += lds[ci * RS + r*64 + w4*4 + j];
        xt4[((size_t)b * 256 + hp4*16 + w4) * C_ + c0 + ci] = f2bf(s * 0.0625f);
    }
    #pragma unroll
    for (int i = 0; i < 2; ++i) {
        int v = i * 256 + t;
        int w4 = v & 15, ci = v >> 4;
        float s = 0.f;
        #pragma unroll
        for (int r = 0; r < 4; ++r)
            #pragma unroll
            for (int j = 0; j < 4; ++j) s += lds[ci * RS + r*64 + w4*4 + j];
        xtT4[((size_t)(b * C_ + c0 + ci)) * 256 + hp4*16 + w4] = f2bf(s * 0.0625f);
    }
}

// ---------------- MFMA flash attention body (round-10, proven config).
// KVBLK=64, split K/V double buffers (4 x 16 KB), counted-vmcnt schedule.
template<int N, int SPLIT>
__device__ __forceinline__ void attn_body(const unsigned short* __restrict__ xt,
                                          const unsigned short* __restrict__ xtT,
                                          unsigned short* __restrict__ op,
                                          float* __restrict__ ml,
                                          const int bid, char* lds) {
    constexpr int LOG2S = (SPLIT == 2) ? 1 : ((SPLIT == 4) ? 2 : 3);
    constexpr int QB = N / 128;
    constexpr int W2 = QB * SPLIT / 2;
    constexpr int NT = N / SPLIT / 64;
    static_assert(NT >= 2 && (NT & 1) == 0, "even NT >= 2 required");
    const int xcd   = bid & 7;
    const int b     = xcd >> 1;                 // batch pinned to XCD pair (L2 locality)
    const int wi    = (xcd & 1) * W2 + (bid >> 3);
    const int split = wi & (SPLIT - 1);
    const int qx    = wi >> LOG2S;
    const int n0    = qx * 128;
    const int m_beg = split * (N / SPLIT);

    const int tid = threadIdx.x;
    const int w = tid >> 6, lane = tid & 63;
    const int g = lane >> 4, rho = lane & 15;

    const char* xb  = (const char*)(xt  + (size_t)b * N * C_);
    const char* xtb = (const char*)(xtT + (size_t)b * C_ * N);

    bf16x8 qf[2][4];
    #pragma unroll
    for (int tt = 0; tt < 2; ++tt) {
        const char* qr = xb + (size_t)(n0 + w * 32 + tt * 16 + rho) * 256;
        #pragma unroll
        for (int kc = 0; kc < 4; ++kc) {
            bf16x8 raw = *(const bf16x8*)(qr + kc * 64 + g * 16);
            bf16x8 s;
            #pragma unroll
            for (int e = 0; e < 8; ++e)
                s[e] = (short)f2bf(bf2f((unsigned short)raw[e]) * LOG2E);
            qf[tt][kc] = s;
        }
    }

    int kOff[4], vOff[4];
    #pragma unroll
    for (int k = 0; k < 4; ++k) {
        int D = (w * 4 + k) * 1024 + lane * 16;
        int row = D >> 8, colb = D & 255;
        kOff[k] = row * 256 + (colb ^ ((row & 15) << 4));
        int c = D >> 7, cb2 = D & 127;
        vOff[k] = c * (2 * N) + (cb2 ^ ((c & 7) << 4));
    }
    int qkOff[4][4], pvOff[8][2];
    #pragma unroll
    for (int mb = 0; mb < 4; ++mb) {
        int rowm = ((mb >> 1) << 5) + ((mb & 1) << 2) + ((rho >> 2) << 3) + (rho & 3);
        int swz = (rowm & 15) << 4;
        #pragma unroll
        for (int kc = 0; kc < 4; ++kc)
            qkOff[mb][kc] = rowm * 256 + ((kc * 64 + g * 16) ^ swz);
    }
    #pragma unroll
    for (int cb = 0; cb < 8; ++cb) {
        int c = cb * 16 + rho;
        int vswz = (c & 7) << 4;
        #pragma unroll
        for (int ks = 0; ks < 2; ++ks)
            pvOff[cb][ks] = c * 128 + ((ks * 64 + g * 16) ^ vswz);
    }

    char* const KB0 = lds;
    char* const KB1 = lds + 16384;
    char* const VB0 = lds + 32768;
    char* const VB1 = lds + 49152;
    const char* kG = xb  + (size_t)m_beg * 256;
    const char* vG = xtb + (size_t)m_beg * 2;

    auto stageK = [&](char* dst, int tile) {
        const char* s = kG + (size_t)tile * (64 * 256);
        #pragma unroll
        for (int k = 0; k < 4; ++k) gload_lds16(s + kOff[k], dst + (w * 4 + k) * 1024);
    };
    auto stageV = [&](char* dst, int tile) {
        const char* s = vG + (size_t)tile * (64 * 2);
        #pragma unroll
        for (int k = 0; k < 4; ++k) gload_lds16(s + vOff[k], dst + (w * 4 + k) * 1024);
    };

    f32x4 acc[2][8];
    #pragma unroll
    for (int tt = 0; tt < 2; ++tt)
        #pragma unroll
        for (int cb = 0; cb < 8; ++cb) acc[tt][cb] = (f32x4){0.f, 0.f, 0.f, 0.f};
    float m_run[2] = {-INFINITY, -INFINITY};
    float l_lane[2] = {0.f, 0.f};

    auto qkt = [&](const char* kb, f32x4 (&aS)[2][4]) {
        #pragma unroll
        for (int tt = 0; tt < 2; ++tt)
            #pragma unroll
            for (int mb = 0; mb < 4; ++mb) aS[tt][mb] = (f32x4){0.f, 0.f, 0.f, 0.f};
        #pragma unroll
        for (int mb = 0; mb < 4; ++mb)
            #pragma unroll
            for (int kc = 0; kc < 4; ++kc) {
                bf16x8 kf = *(const bf16x8*)(kb + qkOff[mb][kc]);
                aS[0][mb] = __builtin_amdgcn_mfma_f32_16x16x32_bf16(kf, qf[0][kc], aS[0][mb], 0, 0, 0);
                aS[1][mb] = __builtin_amdgcn_mfma_f32_16x16x32_bf16(kf, qf[1][kc], aS[1][mb], 0, 0, 0);
            }
    };

    auto smpv = [&](f32x4 (&aS)[2][4], const char* vb) {
        bf16x8 pb[2][2];
        #pragma unroll
        for (int tt = 0; tt < 2; ++tt) {
            float tm = aS[tt][0][0];
            #pragma unroll
            for (int mb = 0; mb < 4; ++mb)
                #pragma unroll
                for (int r = 0; r < 4; ++r) tm = fmaxf(tm, aS[tt][mb][r]);
            tm = fmaxf(tm, __shfl_xor(tm, 16));
            tm = fmaxf(tm, __shfl_xor(tm, 32));
            if (!__all(tm <= m_run[tt] + 6.0f)) {
                float nm = fmaxf(m_run[tt], tm);
                float sc = ex2(m_run[tt] - nm);
                l_lane[tt] *= sc;
                m_run[tt] = nm;
                #pragma unroll
                for (int cb = 0; cb < 8; ++cb) {
                    acc[tt][cb][0] *= sc; acc[tt][cb][1] *= sc;
                    acc[tt][cb][2] *= sc; acc[tt][cb][3] *= sc;
                }
            }
            float p[4][4];
            #pragma unroll
            for (int mb = 0; mb < 4; ++mb)
                #pragma unroll
                for (int r = 0; r < 4; ++r) {
                    p[mb][r] = ex2(aS[tt][mb][r] - m_run[tt]);
                    l_lane[tt] += p[mb][r];
                }
            #pragma unroll
            for (int ks = 0; ks < 2; ++ks) {
                union { bf16x8 v; unsigned int u[4]; } pk;
                pk.u[0] = pkbf(p[2 * ks][0],     p[2 * ks][1]);
                pk.u[1] = pkbf(p[2 * ks][2],     p[2 * ks][3]);
                pk.u[2] = pkbf(p[2 * ks + 1][0], p[2 * ks + 1][1]);
                pk.u[3] = pkbf(p[2 * ks + 1][2], p[2 * ks + 1][3]);
                pb[tt][ks] = pk.v;
            }
        }
        #pragma unroll
        for (int cb = 0; cb < 8; ++cb)
            #pragma unroll
            for (int ks = 0; ks < 2; ++ks) {
                bf16x8 vf = *(const bf16x8*)(vb + pvOff[cb][ks]);
                acc[0][cb] = __builtin_amdgcn_mfma_f32_16x16x32_bf16(vf, pb[0][ks], acc[0][cb], 0, 0, 0);
                acc[1][cb] = __builtin_amdgcn_mfma_f32_16x16x32_bf16(vf, pb[1][ks], acc[1][cb], 0, 0, 0);
            }
    };

    f32x4 accA[2][4], accB[2][4];

    stageK(KB0, 0); stageV(VB0, 0); stageK(KB1, 1); stageV(VB1, 1);
    asm volatile("s_waitcnt vmcnt(12)" ::: "memory");
    __builtin_amdgcn_s_barrier();
    qkt(KB0, accA);
    __builtin_amdgcn_s_barrier();
    if constexpr (NT > 2) stageK(KB0, 2);

    #pragma unroll 1
    for (int j = 0; j + 3 < NT; j += 2) {
        asm volatile("s_waitcnt vmcnt(8)" ::: "memory");
        __builtin_amdgcn_s_barrier();
        qkt(KB1, accB);
        smpv(accA, VB0);
        __builtin_amdgcn_s_barrier();
        stageK(KB1, j + 3);
        stageV(VB0, j + 2);
        asm volatile("s_waitcnt vmcnt(8)" ::: "memory");
        __builtin_amdgcn_s_barrier();
        qkt(KB0, accA);
        smpv(accB, VB1);
        __builtin_amdgcn_s_barrier();
        if (j + 4 < NT) stageK(KB0, j + 4);
        stageV(VB1, j + 3);
    }
    asm volatile("s_waitcnt vmcnt(4)" ::: "memory");
    __builtin_amdgcn_s_barrier();
    qkt(KB1, accB);
    smpv(accA, VB0);
    asm volatile("s_waitcnt vmcnt(0)" ::: "memory");
    __builtin_amdgcn_s_barrier();
    smpv(accB, VB1);

    #pragma unroll
    for (int tt = 0; tt < 2; ++tt) {
        l_lane[tt] += __shfl_xor(l_lane[tt], 16);
        l_lane[tt] += __shfl_xor(l_lane[tt], 32);
        const int n = n0 + w * 32 + tt * 16 + rho;
        #pragma unroll
        for (int cb = 0; cb < 8; ++cb)
            #pragma unroll
            for (int r = 0; r < 4; ++r)
                op[((size_t)(split * B_ + b) * C_ + cb * 16 + g * 4 + r) * N + n] = f2bf(acc[tt][cb][r]);
        if (g == 0) {
            ml[((size_t)(split * B_ + b) * N + n) * 2 + 0] = m_run[tt];
            ml[((size_t)(split * B_ + b) * N + n) * 2 + 1] = l_lane[tt];
        }
    }
}

// ONE launch for all three scales. Small blocks FIRST and SHORT (r14's proven
// shape: 256 scale-2 SPLIT=8 NT=2 + 16 scale-4 SPLIT=2 NT=2) so they clear
// their resident slots fast; scale-1 blocks (272..783) backfill.
__global__ __launch_bounds__(256, 2) void attn_fused(const unsigned short* __restrict__ xt1,
                                                     const unsigned short* __restrict__ xtT1,
                                                     unsigned short* __restrict__ o1p,
                                                     float* __restrict__ ml1,
                                                     const unsigned short* __restrict__ xt2,
                                                     const unsigned short* __restrict__ xtT2,
                                                     unsigned short* __restrict__ a2p,
                                                     float* __restrict__ ml2,
                                                     const unsigned short* __restrict__ xt4,
                                                     const unsigned short* __restrict__ xtT4,
                                                     unsigned short* __restrict__ a4p,
                                                     float* __restrict__ ml4) {
    __shared__ char lds[65536];
    const int bid = (int)blockIdx.x;
    if (bid < 256)
        attn_body<1024, 8>(xt2, xtT2, a2p, ml2, bid, lds);
    else if (bid < 272)
        attn_body<256, 2>(xt4, xtT4, a4p, ml4, bid - 256, lds);
    else
        attn_body<4096, 4>(xt1, xtT1, o1p, ml1, bid - 272, lds);
}

// ---------------- fused merge + upsample + scale-1 merge.
// One block per (b,c): 8-way-merge scale-2 partials and 2-way scale-4 into
// LDS (f32), then per-pixel scale-1 4-way merge + two bilinear adds from LDS.
__global__ __launch_bounds__(256) void combine2(float* __restrict__ out,
                                                const unsigned short* __restrict__ o1p,
                                                const float* __restrict__ ml1,
                                                const unsigned short* __restrict__ a2p,
                                                const float* __restrict__ ml2,
                                                const unsigned short* __restrict__ a4p,
                                                const float* __restrict__ ml4) {
    __shared__ float a2s[1024];
    __shared__ float a4s[256];
    const int bc = (int)blockIdx.x;
    const int b  = bc >> 7;
    const int c  = bc & 127;
    const int t  = threadIdx.x;

    #pragma unroll
    for (int i = 0; i < 4; ++i) {
        int n = i * 256 + t;
        float M = -INFINITY;
        #pragma unroll
        for (int s = 0; s < 8; ++s) M = fmaxf(M, ml2[((s * 4 + b) * 1024 + n) * 2]);
        float L = 0.f, O = 0.f;
        #pragma unroll
        for (int s = 0; s < 8; ++s) {
            float wgt = ex2(ml2[((s * 4 + b) * 1024 + n) * 2] - M);
            L += ml2[((s * 4 + b) * 1024 + n) * 2 + 1] * wgt;
            O += bf2f(a2p[((size_t)((s * 4 + b) * 128 + c)) * 1024 + n]) * wgt;
        }
        a2s[n] = O / L;
    }
    {
        int n = t;
        float m0 = ml4[((0 * 4 + b) * 256 + n) * 2], l0 = ml4[((0 * 4 + b) * 256 + n) * 2 + 1];
        float m1 = ml4[((1 * 4 + b) * 256 + n) * 2], l1 = ml4[((1 * 4 + b) * 256 + n) * 2 + 1];
        float M  = fmaxf(m0, m1);
        float w0 = ex2(m0 - M), w1 = ex2(m1 - M);
        float O  = bf2f(a4p[((size_t)((0 * 4 + b) * 128 + c)) * 256 + n]) * w0
                 + bf2f(a4p[((size_t)((1 * 4 + b) * 128 + c)) * 256 + n]) * w1;
        a4s[n] = O / (l0 * w0 + l1 * w1);
    }
    __syncthreads();

    #pragma unroll
    for (int i = 0; i < 16; ++i) {
        int e = i * 256 + t;
        int h = e >> 6, w = e & 63;
        float M = -INFINITY;
        #pragma unroll
        for (int s = 0; s < 4; ++s) M = fmaxf(M, ml1[((size_t)(s * 4 + b) * 4096 + e) * 2]);
        float num = 0.f, den = 0.f;
        #pragma unroll
        for (int s = 0; s < 4; ++s) {
            float wgt = ex2(ml1[((size_t)(s * 4 + b) * 4096 + e) * 2] - M);
            den += ml1[((size_t)(s * 4 + b) * 4096 + e) * 2 + 1] * wgt;
            num += bf2f(o1p[((size_t)(s * 512 + bc)) * 4096 + e]) * wgt;
        }
        float v = num / den;
        {
            float sh = (h + 0.5f) * 0.5f - 0.5f;
            float sw = (w + 0.5f) * 0.5f - 0.5f;
            int h0 = (int)floorf(sh); float fh = sh - (float)h0;
            int w0 = (int)floorf(sw); float fw = sw - (float)w0;
            int h0c = max(h0, 0), h1c = min(h0 + 1, 31);
            int w0c = max(w0, 0), w1c = min(w0 + 1, 31);
            float v00 = a2s[h0c * 32 + w0c], v01 = a2s[h0c * 32 + w1c];
            float v10 = a2s[h1c * 32 + w0c], v11 = a2s[h1c * 32 + w1c];
            v += (1.f - fh) * ((1.f - fw) * v00 + fw * v01)
               +        fh  * ((1.f - fw) * v10 + fw * v11);
        }
        {
            float sh = (h + 0.5f) * 0.25f - 0.5f;
            float sw = (w + 0.5f) * 0.25f - 0.5f;
            int h0 = (int)floorf(sh); float fh = sh - (float)h0;
            int w0 = (int)floorf(sw); float fw = sw - (float)w0;
            int h0c = max(h0, 0), h1c = min(h0 + 1, 15);
            int w0c = max(w0, 0), w1c = min(w0 + 1, 15);
            float v00 = a4s[h0c * 16 + w0c], v01 = a4s[h0c * 16 + w1c];
            float v10 = a4s[h1c * 16 + w0c], v11 = a4s[h1c * 16 + w1c];
            v += (1.f - fh) * ((1.f - fw) * v00 + fw * v01)
               +        fh  * ((1.f - fw) * v10 + fw * v11);
        }
        out[(size_t)bc * 4096 + e] = v;
    }
}

extern "C" void kernel_launch(void* const* d_in, const int* in_sizes, int n_in,
                              void* d_out, int out_size, void* d_ws, size_t ws_size,
                              hipStream_t stream) {
    const float* x = (const float*)d_in[0];
    float* out = (float*)d_out;
    char* ws = (char*)d_ws;
    unsigned short* xt1  = (unsigned short*)(ws + XT1_B);
    unsigned short* xtT1 = (unsigned short*)(ws + XTT1_B);
    unsigned short* o1p  = (unsigned short*)(ws + O1P_B);
    float*          ml1  = (float*)(ws + ML1_B);
    unsigned short* xt2  = (unsigned short*)(ws + XT2_B);
    unsigned short* xtT2 = (unsigned short*)(ws + XTT2_B);
    unsigned short* xt4  = (unsigned short*)(ws + XT4_B);
    unsigned short* xtT4 = (unsigned short*)(ws + XTT4_B);
    unsigned short* a2p  = (unsigned short*)(ws + A2P_B);
    float*          ml2  = (float*)(ws + ML2_B);
    unsigned short* a4p  = (unsigned short*)(ws + A4P_B);
    float*          ml4  = (float*)(ws + ML4_B);

    pool_all<<<dim3(16, 4, B_), 256, 0, stream>>>(x, xt1, xtT1, xt2, xtT2, xt4, xtT4);
    attn_fused<<<784, 256, 0, stream>>>(xt1, xtT1, o1p, ml1,
                                        xt2, xtT2, a2p, ml2,
                                        xt4, xtT4, a4p, ml4);
    combine2<<<512, 256, 0, stream>>>(out, o1p, ml1, a2p, ml2, a4p, ml4);
}